// Round 1
// baseline (28579.980 us; speedup 1.0000x reference)
//
#include <hip/hip_runtime.h>
#include <hip/hip_cooperative_groups.h>

namespace cg = cooperative_groups;

typedef __bf16 bf16x8 __attribute__((ext_vector_type(8)));
typedef float f32x4 __attribute__((ext_vector_type(4)));

__device__ inline float sigm(float x) { return 1.0f / (1.0f + __expf(-x)); }
__device__ inline float tanh_f(float x) {
    float e = __expf(2.0f * x);
    return 1.0f - 2.0f / (e + 1.0f);
}

__device__ inline unsigned short f2bf(float f) {
    __bf16 h = (__bf16)f;
    return __builtin_bit_cast(unsigned short, h);
}

__device__ inline bf16x8 cvt8(float4 lo, float4 hi) {
    bf16x8 r;
    r[0] = (__bf16)lo.x; r[1] = (__bf16)lo.y; r[2] = (__bf16)lo.z; r[3] = (__bf16)lo.w;
    r[4] = (__bf16)hi.x; r[5] = (__bf16)hi.y; r[6] = (__bf16)hi.z; r[7] = (__bf16)hi.w;
    return r;
}

// ---------------------------------------------------------------------------
// Weight conversion: W{x,h}{0,1} fp32 [4096][1024] -> Wcat bf16 [4096][2048]
// (row g: k<1024 = Wx[g][k], k>=1024 = Wh[g][k-1024])
// ---------------------------------------------------------------------------
__global__ void cvt_weights(const float* __restrict__ Wx0, const float* __restrict__ Wh0,
                            const float* __restrict__ Wx1, const float* __restrict__ Wh1,
                            unsigned short* __restrict__ W0, unsigned short* __restrict__ W1) {
    size_t idx = ((size_t)blockIdx.x * 256 + threadIdx.x) * 8;
    const size_t LSZ = (size_t)4096 * 2048;
    int layer = idx >= LSZ;
    size_t e = idx - (layer ? LSZ : 0);
    int row = (int)(e >> 11);
    int k = (int)(e & 2047);
    const float* src = layer ? (k < 1024 ? Wx1 : Wh1) : (k < 1024 ? Wx0 : Wh0);
    const float* s = src + (size_t)row * 1024 + (k & 1023);
    float4 lo = ((const float4*)s)[0], hi = ((const float4*)s)[1];
    *reinterpret_cast<bf16x8*>((layer ? W1 : W0) + e) = cvt8(lo, hi);
}

// sequence [B][T][I] fp32 -> seqb [T][B][I] bf16
__global__ void cvt_seq(const float* __restrict__ seq, unsigned short* __restrict__ seqb, int T) {
    int t = blockIdx.x >> 6, b = blockIdx.x & 63;
    const float* s = seq + ((size_t)b * T + t) * 1024 + threadIdx.x * 8;
    float4 lo = ((const float4*)s)[0], hi = ((const float4*)s)[1];
    *reinterpret_cast<bf16x8*>(seqb + ((size_t)t * 64 + b) * 1024 + threadIdx.x * 8) = cvt8(lo, hi);
}

// ---------------------------------------------------------------------------
// Persistent pipelined 2-layer LSTM.
// Grid: 256 blocks x 256 threads (1 block/CU). 513 phases, 1 grid.sync each.
// Block decode (XCD swizzle: b-split pair of a jtile shares bid%8 -> same XCD):
//   bid = (jtile&7) + 8*(( (layer*8 + (jtile>>3)) * 2 + btile ))
// Each block: layer (0/1), btile (rows btile*32..+31), jtile (cols jtile*16..+15, x4 gates)
// Wave w handles gate w, both 16-row M-tiles. K-loop = 64 iters of K=32 (x-part + h-part).
// ---------------------------------------------------------------------------
template <bool SEQB>
__global__ __launch_bounds__(256, 1) void lstm_persistent(
    const float* __restrict__ seq, const unsigned short* __restrict__ seqb,
    const unsigned short* __restrict__ W0, const unsigned short* __restrict__ W1,
    const float* __restrict__ bias0, const float* __restrict__ bias1,
    unsigned short* h0buf, unsigned short* h1buf, float* c0, float* c1,
    float* out, int T) {
    cg::grid_group grid = cg::this_grid();

    const int bid = blockIdx.x;
    const int r = bid & 7, q = bid >> 3;
    const int btile = q & 1, t2 = q >> 1;     // t2: 0..15
    const int layer = t2 >> 3;                // 0/1
    const int jtile = ((t2 & 7) << 3) | r;    // 0..63
    const int j0 = jtile * 16;
    const int brow = btile * 32;

    const int tid = threadIdx.x;
    const int wave = tid >> 6, lane = tid & 63;
    const int ln15 = lane & 15, lhi = lane >> 4;

    const unsigned short* Wl = layer ? W1 : W0;
    const float* bias = layer ? bias1 : bias0;
    // B fragment base: row = gate*1024 + j0 + (lane&15), k-offset (lane>>4)*8
    const unsigned short* Bbase = Wl + (size_t)(wave * 1024 + j0 + ln15) * 2048 + lhi * 8;
    float* cp = layer ? c1 : c0;
    unsigned short* hown = layer ? h1buf : h0buf;

    __shared__ float zsm[4][32][16];

    for (int p = 0; p <= T; ++p) {
        const bool act = layer ? (p >= 1) : (p < T);
        if (act) {
            const int t = layer ? (p - 1) : p;
            f32x4 acc0 = {0.f, 0.f, 0.f, 0.f};
            f32x4 acc1 = {0.f, 0.f, 0.f, 0.f};
            const unsigned short* bp = Bbase;

            // ---- x-part: K = 0..1023 ----
            if (layer == 0 && !SEQB) {
                // on-the-fly fp32 -> bf16 from seq [B][T][I]
                const float* a0f = seq + ((size_t)(brow + ln15) * T + t) * 1024 + lhi * 8;
                const float* a1f = a0f + (size_t)16 * T * 1024;
#pragma unroll 4
                for (int kk = 0; kk < 32; ++kk) {
                    float4 l0 = ((const float4*)a0f)[0], h0v = ((const float4*)a0f)[1];
                    float4 l1 = ((const float4*)a1f)[0], h1v = ((const float4*)a1f)[1];
                    bf16x8 av0 = cvt8(l0, h0v), av1 = cvt8(l1, h1v);
                    bf16x8 bv = *((const bf16x8*)bp);
                    acc0 = __builtin_amdgcn_mfma_f32_16x16x32_bf16(av0, bv, acc0, 0, 0, 0);
                    acc1 = __builtin_amdgcn_mfma_f32_16x16x32_bf16(av1, bv, acc1, 0, 0, 0);
                    a0f += 32; a1f += 32; bp += 32;
                }
            } else {
                const unsigned short* xsrc =
                    (layer == 0) ? (seqb + (size_t)t * 65536)
                                 : (h0buf + (size_t)((p - 1) & 1) * 65536);
                const unsigned short* a0 = xsrc + (size_t)(brow + ln15) * 1024 + lhi * 8;
                const unsigned short* a1 = a0 + 16 * 1024;
#pragma unroll 4
                for (int kk = 0; kk < 32; ++kk) {
                    bf16x8 av0 = *((const bf16x8*)a0);
                    bf16x8 av1 = *((const bf16x8*)a1);
                    bf16x8 bv = *((const bf16x8*)bp);
                    acc0 = __builtin_amdgcn_mfma_f32_16x16x32_bf16(av0, bv, acc0, 0, 0, 0);
                    acc1 = __builtin_amdgcn_mfma_f32_16x16x32_bf16(av1, bv, acc1, 0, 0, 0);
                    a0 += 32; a1 += 32; bp += 32;
                }
            }

            // ---- h-part: K = 1024..2047 ----
            {
                const unsigned short* hsrc =
                    (layer == 0) ? (h0buf + (size_t)((p + 1) & 1) * 65536)
                                 : (h1buf + (size_t)(p & 1) * 65536);
                const unsigned short* a0 = hsrc + (size_t)(brow + ln15) * 1024 + lhi * 8;
                const unsigned short* a1 = a0 + 16 * 1024;
#pragma unroll 4
                for (int kk = 0; kk < 32; ++kk) {
                    bf16x8 av0 = *((const bf16x8*)a0);
                    bf16x8 av1 = *((const bf16x8*)a1);
                    bf16x8 bv = *((const bf16x8*)bp);
                    acc0 = __builtin_amdgcn_mfma_f32_16x16x32_bf16(av0, bv, acc0, 0, 0, 0);
                    acc1 = __builtin_amdgcn_mfma_f32_16x16x32_bf16(av1, bv, acc1, 0, 0, 0);
                    a0 += 32; a1 += 32; bp += 32;
                }
            }

            // ---- epilogue: exchange gates via LDS, update c/h ----
            // D layout (verified m89): col = lane&15, row = (lane>>4)*4 + reg
#pragma unroll
            for (int rr = 0; rr < 4; ++rr) {
                zsm[wave][4 * lhi + rr][ln15] = acc0[rr];
                zsm[wave][16 + 4 * lhi + rr][ln15] = acc1[rr];
            }
            __syncthreads();

            const int wout = layer ? ((p + 1) & 1) : (p & 1);
#pragma unroll
            for (int e0 = 0; e0 < 2; ++e0) {
                int e = tid + e0 * 256;        // 0..511 over [32 b][16 j]
                int bl = e >> 4, jj = e & 15;
                float fz = zsm[0][bl][jj] + bias[j0 + jj];
                float wz = zsm[1][bl][jj] + bias[1024 + j0 + jj];
                float iz = zsm[2][bl][jj] + bias[2048 + j0 + jj];
                float mz = zsm[3][bl][jj] + bias[3072 + j0 + jj];
                int bg = brow + bl, jg = j0 + jj;
                size_t idx = (size_t)bg * 1024 + jg;
                float cold = cp[idx];
                float cnew = cold * sigm(fz) + sigm(wz) * tanh_f(iz);
                float h = tanh_f(cnew) * sigm(mz);
                cp[idx] = cnew;
                hown[(size_t)wout * 65536 + idx] = f2bf(h);
                if (layer && p == T) out[idx] = h;  // final h of layer 1
            }
        }
        grid.sync();
    }
}

// ---------------------------------------------------------------------------
extern "C" void kernel_launch(void* const* d_in, const int* in_sizes, int n_in,
                              void* d_out, int out_size, void* d_ws, size_t ws_size,
                              hipStream_t stream) {
    const float* seq = (const float*)d_in[0];
    const float* Wx0 = (const float*)d_in[1];
    const float* Wh0 = (const float*)d_in[2];
    const float* b0 = (const float*)d_in[3];
    const float* Wx1 = (const float*)d_in[4];
    const float* Wh1 = (const float*)d_in[5];
    const float* b1 = (const float*)d_in[6];
    float* out = (float*)d_out;
    char* ws = (char*)d_ws;
    const int T = 512;

    const size_t WBYTES = (size_t)4096 * 2048 * 2;        // 16.78 MB per layer
    const size_t SEQB_BYTES = (size_t)512 * 64 * 1024 * 2; // 67.1 MB
    const size_t STATE_BYTES = 4 * 262144;                 // h0[2],h1[2] bf16 + c0,c1 fp32

    size_t offSeqb = 2 * WBYTES;
    bool big = ws_size >= 2 * WBYTES + SEQB_BYTES + STATE_BYTES;
    size_t offState = big ? (offSeqb + SEQB_BYTES) : offSeqb;

    unsigned short* W0p = (unsigned short*)(ws);
    unsigned short* W1p = (unsigned short*)(ws + WBYTES);
    unsigned short* seqbp = (unsigned short*)(ws + offSeqb);
    unsigned short* h0p = (unsigned short*)(ws + offState);
    unsigned short* h1p = (unsigned short*)(ws + offState + 262144);
    float* c0p = (float*)(ws + offState + 2 * 262144);
    float* c1p = (float*)(ws + offState + 3 * 262144);

    hipLaunchKernelGGL(cvt_weights, dim3(8192), dim3(256), 0, stream,
                       Wx0, Wh0, Wx1, Wh1, W0p, W1p);
    if (big)
        hipLaunchKernelGGL(cvt_seq, dim3(T * 64), dim3(128), 0, stream, seq, seqbp, T);
    hipMemsetAsync(ws + offState, 0, STATE_BYTES, stream);

    int Tv = T;
    void* args[] = {&seq, &seqbp, &W0p, &W1p, &b0, &b1, &h0p, &h1p, &c0p, &c1p, &out, &Tv};
    if (big) {
        hipLaunchCooperativeKernel((void*)lstm_persistent<true>, dim3(256), dim3(256),
                                   args, 0, stream);
    } else {
        hipLaunchCooperativeKernel((void*)lstm_persistent<false>, dim3(256), dim3(256),
                                   args, 0, stream);
    }
}

// Round 2
// 14044.632 us; speedup vs baseline: 2.0349x; 2.0349x over previous
//
#include <hip/hip_runtime.h>

typedef __bf16 bf16x8 __attribute__((ext_vector_type(8)));
typedef float f32x4 __attribute__((ext_vector_type(4)));
typedef unsigned long long u64;

__device__ inline float sigm(float x) { return 1.0f / (1.0f + __expf(-x)); }
__device__ inline float tanh_f(float x) {
    float e = __expf(2.0f * x);
    return 1.0f - 2.0f / (e + 1.0f);
}

__device__ inline unsigned short f2bf(float f) {
    __bf16 h = (__bf16)f;
    return __builtin_bit_cast(unsigned short, h);
}

__device__ inline bf16x8 cvt8(float4 lo, float4 hi) {
    bf16x8 r;
    r[0] = (__bf16)lo.x; r[1] = (__bf16)lo.y; r[2] = (__bf16)lo.z; r[3] = (__bf16)lo.w;
    r[4] = (__bf16)hi.x; r[5] = (__bf16)hi.y; r[6] = (__bf16)hi.z; r[7] = (__bf16)hi.w;
    return r;
}

// ---------------------------------------------------------------------------
// Weight conversion: W{x,h}{0,1} fp32 [4096][1024] -> Wcat bf16 [4096][2048]
// ---------------------------------------------------------------------------
__global__ void cvt_weights(const float* __restrict__ Wx0, const float* __restrict__ Wh0,
                            const float* __restrict__ Wx1, const float* __restrict__ Wh1,
                            unsigned short* __restrict__ W0, unsigned short* __restrict__ W1) {
    size_t idx = ((size_t)blockIdx.x * 256 + threadIdx.x) * 8;
    const size_t LSZ = (size_t)4096 * 2048;
    int layer = idx >= LSZ;
    size_t e = idx - (layer ? LSZ : 0);
    int row = (int)(e >> 11);
    int k = (int)(e & 2047);
    const float* src = layer ? (k < 1024 ? Wx1 : Wh1) : (k < 1024 ? Wx0 : Wh0);
    const float* s = src + (size_t)row * 1024 + (k & 1023);
    float4 lo = ((const float4*)s)[0], hi = ((const float4*)s)[1];
    *reinterpret_cast<bf16x8*>((layer ? W1 : W0) + e) = cvt8(lo, hi);
}

// sequence [B][T][I] fp32 -> seqb [T][B][I] bf16
__global__ void cvt_seq(const float* __restrict__ seq, unsigned short* __restrict__ seqb, int T) {
    int t = blockIdx.x >> 6, b = blockIdx.x & 63;
    const float* s = seq + ((size_t)b * T + t) * 1024 + threadIdx.x * 8;
    float4 lo = ((const float4*)s)[0], hi = ((const float4*)s)[1];
    *reinterpret_cast<bf16x8*>(seqb + ((size_t)t * 64 + b) * 1024 + threadIdx.x * 8) = cvt8(lo, hi);
}

// ---------------------------------------------------------------------------
// LDS: staged A tile (32 rows x 1024 bf16, 16B slots XOR-swizzled by row&7)
// union'd with the gate-exchange buffer (phases are syncthreads-separated).
// ---------------------------------------------------------------------------
union SmemU {
    unsigned short a[32][1024];  // 64 KB
    float z[4][32][16];          // 8 KB
};

struct StageRegs { u64 q[32]; };

__device__ inline void stage_load(StageRegs& r, const unsigned short* __restrict__ src) {
#pragma unroll
    for (int i = 0; i < 16; ++i) {
        int chunk = (int)threadIdx.x + (i << 8);  // 0..4095
        int row = chunk >> 7;                     // 0..31
        int slot = chunk & 127;                   // 16B slot
        const unsigned short* s = src + row * 1024 + slot * 8;
        r.q[2 * i] = __hip_atomic_load((const u64*)s, __ATOMIC_RELAXED, __HIP_MEMORY_SCOPE_AGENT);
        r.q[2 * i + 1] = __hip_atomic_load((const u64*)(s + 4), __ATOMIC_RELAXED, __HIP_MEMORY_SCOPE_AGENT);
    }
}

__device__ inline void stage_write(const StageRegs& r, SmemU& sm) {
#pragma unroll
    for (int i = 0; i < 16; ++i) {
        int chunk = (int)threadIdx.x + (i << 8);
        int row = chunk >> 7;
        int slot = chunk & 127;
        int sw = slot ^ (row & 7);
        u64* d = (u64*)&sm.a[row][sw * 8];
        d[0] = r.q[2 * i];
        d[1] = r.q[2 * i + 1];
    }
}

// MFMA over one K-part (1024 wide) with A from swizzled LDS, B from L2-cached global.
__device__ inline void mfma_lds(const SmemU& sm, const unsigned short* __restrict__ bp,
                                f32x4& acc0, f32x4& acc1, int ln15, int lhi) {
#pragma unroll 4
    for (int kk = 0; kk < 32; ++kk) {
        int slot = kk * 4 + lhi;
        int sw = (slot ^ (ln15 & 7)) * 8;
        bf16x8 av0 = *(const bf16x8*)&sm.a[ln15][sw];
        bf16x8 av1 = *(const bf16x8*)&sm.a[16 + ln15][sw];
        bf16x8 bv = *((const bf16x8*)(bp + kk * 32));
        acc0 = __builtin_amdgcn_mfma_f32_16x16x32_bf16(av0, bv, acc0, 0, 0, 0);
        acc1 = __builtin_amdgcn_mfma_f32_16x16x32_bf16(av1, bv, acc1, 0, 0, 0);
    }
}

// ---------------------------------------------------------------------------
// Persistent pipelined 2-layer LSTM, custom lightweight grid barrier.
// 256 blocks x 256 threads (1/CU). Block decode as round 1 (XCD swizzle).
// ---------------------------------------------------------------------------
template <bool SEQB>
__global__ __launch_bounds__(256, 1) void lstm_persistent(
    const float* __restrict__ seq, const unsigned short* __restrict__ seqb,
    const unsigned short* __restrict__ W0, const unsigned short* __restrict__ W1,
    const float* __restrict__ bias0, const float* __restrict__ bias1,
    unsigned short* h0buf, unsigned short* h1buf, unsigned int* bar,
    float* out, int T) {
    const int bid = blockIdx.x;
    const int r = bid & 7, q = bid >> 3;
    const int btile = q & 1, t2 = q >> 1;
    const int layer = t2 >> 3;
    const int jtile = ((t2 & 7) << 3) | r;
    const int j0 = jtile * 16;
    const int brow = btile * 32;

    const int tid = threadIdx.x;
    const int wave = tid >> 6, lane = tid & 63;
    const int ln15 = lane & 15, lhi = lane >> 4;

    const unsigned short* Wl = layer ? W1 : W0;
    const float* bias = layer ? bias1 : bias0;
    const unsigned short* Bbase = Wl + (size_t)(wave * 1024 + j0 + ln15) * 2048 + lhi * 8;
    unsigned short* hown = layer ? h1buf : h0buf;

    __shared__ SmemU smem;

    float creg0 = 0.f, creg1 = 0.f;  // private cell state (fixed thread mapping)
    unsigned int tgt = 0;

    for (int p = 0; p <= T; ++p) {
        const bool act = layer ? (p >= 1) : (p < T);
        if (act) {
            const int t = layer ? (p - 1) : p;
            f32x4 acc0 = {0.f, 0.f, 0.f, 0.f};
            f32x4 acc1 = {0.f, 0.f, 0.f, 0.f};

            if (layer == 0) {
                // issue h-prev staging loads early; hide LLC latency under x-pass
                StageRegs sr;
                stage_load(sr, h0buf + (size_t)((p + 1) & 1) * 65536 + brow * 1024);

                // ---- pass 0: x-part from seqb (cached) or fp32 seq ----
                if (SEQB) {
                    const unsigned short* a0 = seqb + (size_t)t * 65536 + (size_t)(brow + ln15) * 1024 + lhi * 8;
                    const unsigned short* a1 = a0 + 16 * 1024;
                    const unsigned short* bp = Bbase;
#pragma unroll 4
                    for (int kk = 0; kk < 32; ++kk) {
                        bf16x8 av0 = *((const bf16x8*)a0);
                        bf16x8 av1 = *((const bf16x8*)a1);
                        bf16x8 bv = *((const bf16x8*)bp);
                        acc0 = __builtin_amdgcn_mfma_f32_16x16x32_bf16(av0, bv, acc0, 0, 0, 0);
                        acc1 = __builtin_amdgcn_mfma_f32_16x16x32_bf16(av1, bv, acc1, 0, 0, 0);
                        a0 += 32; a1 += 32; bp += 32;
                    }
                } else {
                    const float* a0f = seq + ((size_t)(brow + ln15) * T + t) * 1024 + lhi * 8;
                    const float* a1f = a0f + (size_t)16 * T * 1024;
                    const unsigned short* bp = Bbase;
#pragma unroll 4
                    for (int kk = 0; kk < 32; ++kk) {
                        float4 l0 = ((const float4*)a0f)[0], h0v = ((const float4*)a0f)[1];
                        float4 l1 = ((const float4*)a1f)[0], h1v = ((const float4*)a1f)[1];
                        bf16x8 av0 = cvt8(l0, h0v), av1 = cvt8(l1, h1v);
                        bf16x8 bv = *((const bf16x8*)bp);
                        acc0 = __builtin_amdgcn_mfma_f32_16x16x32_bf16(av0, bv, acc0, 0, 0, 0);
                        acc1 = __builtin_amdgcn_mfma_f32_16x16x32_bf16(av1, bv, acc1, 0, 0, 0);
                        a0f += 32; a1f += 32; bp += 32;
                    }
                }

                // ---- pass 1: h-part via staged LDS ----
                stage_write(sr, smem);
                __syncthreads();
                mfma_lds(smem, Bbase + 1024, acc0, acc1, ln15, lhi);
            } else {
                // ---- pass 0: x-part = h0[t] (coherent, staged) ----
                StageRegs sr;
                stage_load(sr, h0buf + (size_t)((p - 1) & 1) * 65536 + brow * 1024);
                stage_write(sr, smem);
                __syncthreads();
                // issue h1-prev staging loads, then compute pass 0 over them
                stage_load(sr, h1buf + (size_t)(p & 1) * 65536 + brow * 1024);
                mfma_lds(smem, Bbase, acc0, acc1, ln15, lhi);
                __syncthreads();  // all waves done reading smem.a before overwrite
                stage_write(sr, smem);
                __syncthreads();
                // ---- pass 1: h-part via staged LDS ----
                mfma_lds(smem, Bbase + 1024, acc0, acc1, ln15, lhi);
            }

            // ---- epilogue: exchange gates via LDS, update c/h ----
            __syncthreads();  // smem.a reads done before smem.z writes (union)
#pragma unroll
            for (int rr = 0; rr < 4; ++rr) {
                smem.z[wave][4 * lhi + rr][ln15] = acc0[rr];
                smem.z[wave][16 + 4 * lhi + rr][ln15] = acc1[rr];
            }
            __syncthreads();

            const int wout = layer ? ((p + 1) & 1) : (p & 1);
#pragma unroll
            for (int e0 = 0; e0 < 2; ++e0) {
                int e = tid + e0 * 256;
                int bl = e >> 4, jj = e & 15;
                float fz = smem.z[0][bl][jj] + bias[j0 + jj];
                float wz = smem.z[1][bl][jj] + bias[1024 + j0 + jj];
                float iz = smem.z[2][bl][jj] + bias[2048 + j0 + jj];
                float mz = smem.z[3][bl][jj] + bias[3072 + j0 + jj];
                float cold = e0 ? creg1 : creg0;
                float cnew = cold * sigm(fz) + sigm(wz) * tanh_f(iz);
                float h = tanh_f(cnew) * sigm(mz);
                if (e0) creg1 = cnew; else creg0 = cnew;
                int idx = (brow + bl) * 1024 + (j0 + jj);
                __hip_atomic_store(&hown[(size_t)wout * 65536 + idx], f2bf(h),
                                   __ATOMIC_RELAXED, __HIP_MEMORY_SCOPE_AGENT);
                if (layer && p == T) out[idx] = h;
            }
        }

        // ---- lightweight grid barrier (no L2 invalidation) ----
        if (p < T) {
            tgt += 256;
            __syncthreads();  // drains vmcnt: all threads' h-stores visible
            if (tid == 0) {
                __hip_atomic_fetch_add(bar, 1u, __ATOMIC_RELEASE, __HIP_MEMORY_SCOPE_AGENT);
                while (__hip_atomic_load(bar, __ATOMIC_RELAXED, __HIP_MEMORY_SCOPE_AGENT) < tgt)
                    __builtin_amdgcn_s_sleep(2);
            }
            __syncthreads();
            asm volatile("" ::: "memory");
        }
    }
}

// ---------------------------------------------------------------------------
extern "C" void kernel_launch(void* const* d_in, const int* in_sizes, int n_in,
                              void* d_out, int out_size, void* d_ws, size_t ws_size,
                              hipStream_t stream) {
    const float* seq = (const float*)d_in[0];
    const float* Wx0 = (const float*)d_in[1];
    const float* Wh0 = (const float*)d_in[2];
    const float* b0 = (const float*)d_in[3];
    const float* Wx1 = (const float*)d_in[4];
    const float* Wh1 = (const float*)d_in[5];
    const float* b1 = (const float*)d_in[6];
    float* out = (float*)d_out;
    char* ws = (char*)d_ws;
    const int T = 512;

    const size_t WBYTES = (size_t)4096 * 2048 * 2;         // 16.78 MB per layer
    const size_t SEQB_BYTES = (size_t)512 * 64 * 1024 * 2; // 67.1 MB
    const size_t STATE_BYTES = 2 * 262144 + 256;           // h0[2],h1[2] bf16 + bar

    size_t offSeqb = 2 * WBYTES;
    bool big = ws_size >= 2 * WBYTES + SEQB_BYTES + STATE_BYTES;
    size_t offState = big ? (offSeqb + SEQB_BYTES) : offSeqb;

    unsigned short* W0p = (unsigned short*)(ws);
    unsigned short* W1p = (unsigned short*)(ws + WBYTES);
    unsigned short* seqbp = (unsigned short*)(ws + offSeqb);
    unsigned short* h0p = (unsigned short*)(ws + offState);
    unsigned short* h1p = (unsigned short*)(ws + offState + 262144);
    unsigned int* barp = (unsigned int*)(ws + offState + 2 * 262144);

    hipLaunchKernelGGL(cvt_weights, dim3(8192), dim3(256), 0, stream,
                       Wx0, Wh0, Wx1, Wh1, W0p, W1p);
    if (big)
        hipLaunchKernelGGL(cvt_seq, dim3(T * 64), dim3(128), 0, stream, seq, seqbp, T);
    hipMemsetAsync(ws + offState, 0, STATE_BYTES, stream);

    int Tv = T;
    void* args[] = {&seq, &seqbp, &W0p, &W1p, &b0, &b1, &h0p, &h1p, &barp, &out, &Tv};
    if (big) {
        hipLaunchCooperativeKernel((void*)lstm_persistent<true>, dim3(256), dim3(256),
                                   args, 0, stream);
    } else {
        hipLaunchCooperativeKernel((void*)lstm_persistent<false>, dim3(256), dim3(256),
                                   args, 0, stream);
    }
}

// Round 3
// 13010.516 us; speedup vs baseline: 2.1967x; 1.0795x over previous
//
#include <hip/hip_runtime.h>

typedef __bf16 bf16x8 __attribute__((ext_vector_type(8)));
typedef float f32x4 __attribute__((ext_vector_type(4)));
typedef unsigned int u32x4 __attribute__((ext_vector_type(4)));
typedef unsigned long long u64;

__device__ inline float sigm(float x) { return 1.0f / (1.0f + __expf(-x)); }
__device__ inline float tanh_f(float x) {
    float e = __expf(2.0f * x);
    return 1.0f - 2.0f / (e + 1.0f);
}

__device__ inline unsigned short f2bf(float f) {
    __bf16 h = (__bf16)f;
    return __builtin_bit_cast(unsigned short, h);
}

__device__ inline bf16x8 cvt8(float4 lo, float4 hi) {
    bf16x8 r;
    r[0] = (__bf16)lo.x; r[1] = (__bf16)lo.y; r[2] = (__bf16)lo.z; r[3] = (__bf16)lo.w;
    r[4] = (__bf16)hi.x; r[5] = (__bf16)hi.y; r[6] = (__bf16)hi.z; r[7] = (__bf16)hi.w;
    return r;
}

// 16B load that bypasses L1/L2 (LLC-coherent across XCDs), fully pipelined.
__device__ inline u32x4 ld16_bypass(const unsigned short* p) {
    u32x4 r;
    asm volatile("global_load_dwordx4 %0, %1, off sc0 sc1" : "=v"(r) : "v"(p));
    return r;
}

// ---------------------------------------------------------------------------
// Weight conversion: W{x,h}{0,1} fp32 [4096][1024] -> Wcat bf16 [4096][2048]
// ---------------------------------------------------------------------------
__global__ void cvt_weights(const float* __restrict__ Wx0, const float* __restrict__ Wh0,
                            const float* __restrict__ Wx1, const float* __restrict__ Wh1,
                            unsigned short* __restrict__ W0, unsigned short* __restrict__ W1) {
    size_t idx = ((size_t)blockIdx.x * 256 + threadIdx.x) * 8;
    const size_t LSZ = (size_t)4096 * 2048;
    int layer = idx >= LSZ;
    size_t e = idx - (layer ? LSZ : 0);
    int row = (int)(e >> 11);
    int k = (int)(e & 2047);
    const float* src = layer ? (k < 1024 ? Wx1 : Wh1) : (k < 1024 ? Wx0 : Wh0);
    const float* s = src + (size_t)row * 1024 + (k & 1023);
    float4 lo = ((const float4*)s)[0], hi = ((const float4*)s)[1];
    *reinterpret_cast<bf16x8*>((layer ? W1 : W0) + e) = cvt8(lo, hi);
}

// sequence [B][T][I] fp32 -> seqb [T][B][I] bf16
__global__ void cvt_seq(const float* __restrict__ seq, unsigned short* __restrict__ seqb, int T) {
    int t = blockIdx.x >> 6, b = blockIdx.x & 63;
    const float* s = seq + ((size_t)b * T + t) * 1024 + threadIdx.x * 8;
    float4 lo = ((const float4*)s)[0], hi = ((const float4*)s)[1];
    *reinterpret_cast<bf16x8*>(seqb + ((size_t)t * 64 + b) * 1024 + threadIdx.x * 8) = cvt8(lo, hi);
}

// ---------------------------------------------------------------------------
// LDS: two staged A tiles (each 32 x 1024 bf16, 16B slots XOR-swizzled by
// row&7) union'd with the gate-exchange buffer.
// ---------------------------------------------------------------------------
union SmemU {
    unsigned short a[2][32][1024];  // 128 KB
    float z[4][32][16];             // 8 KB
};

struct StageRegs { u32x4 q[16]; };

__device__ inline void stage_issue(StageRegs& r, const unsigned short* __restrict__ src) {
#pragma unroll
    for (int i = 0; i < 16; ++i) {
        int chunk = (int)threadIdx.x + (i << 8);  // 0..4095
        int row = chunk >> 7;                     // 0..31
        int slot = chunk & 127;                   // 16B slot
        r.q[i] = ld16_bypass(src + row * 1024 + slot * 8);
    }
}

__device__ inline void stage_write(const StageRegs& r, unsigned short (&tile)[32][1024]) {
#pragma unroll
    for (int i = 0; i < 16; ++i) {
        int chunk = (int)threadIdx.x + (i << 8);
        int row = chunk >> 7;
        int slot = chunk & 127;
        int sw = slot ^ (row & 7);
        *reinterpret_cast<u32x4*>(&tile[row][sw * 8]) = r.q[i];
    }
}

// MFMA over one K-part (1024 wide) with A from swizzled LDS, B from L2-cached global.
__device__ inline void mfma_lds(const unsigned short (&tile)[32][1024],
                                const unsigned short* __restrict__ bp,
                                f32x4& acc0, f32x4& acc1, int ln15, int lhi) {
#pragma unroll 4
    for (int kk = 0; kk < 32; ++kk) {
        int slot = kk * 4 + lhi;
        int sw = (slot ^ (ln15 & 7)) * 8;
        bf16x8 av0 = *(const bf16x8*)&tile[ln15][sw];
        bf16x8 av1 = *(const bf16x8*)&tile[16 + ln15][sw];
        bf16x8 bv = *((const bf16x8*)(bp + kk * 32));
        acc0 = __builtin_amdgcn_mfma_f32_16x16x32_bf16(av0, bv, acc0, 0, 0, 0);
        acc1 = __builtin_amdgcn_mfma_f32_16x16x32_bf16(av1, bv, acc1, 0, 0, 0);
    }
}

// ---------------------------------------------------------------------------
// Persistent pipelined 2-layer LSTM; distributed-flag grid barrier.
// 256 blocks x 256 threads (1/CU). Block decode as before (XCD swizzle).
// ---------------------------------------------------------------------------
template <bool SEQB>
__global__ __launch_bounds__(256, 1) void lstm_persistent(
    const float* __restrict__ seq, const unsigned short* __restrict__ seqb,
    const unsigned short* __restrict__ W0, const unsigned short* __restrict__ W1,
    const float* __restrict__ bias0, const float* __restrict__ bias1,
    unsigned short* h0buf, unsigned short* h1buf, unsigned int* flags,
    float* out, int T) {
    const int bid = blockIdx.x;
    const int r = bid & 7, q = bid >> 3;
    const int btile = q & 1, t2 = q >> 1;
    const int layer = t2 >> 3;
    const int jtile = ((t2 & 7) << 3) | r;
    const int j0 = jtile * 16;
    const int brow = btile * 32;

    const int tid = threadIdx.x;
    const int wave = tid >> 6, lane = tid & 63;
    const int ln15 = lane & 15, lhi = lane >> 4;

    const unsigned short* Wl = layer ? W1 : W0;
    const float* bias = layer ? bias1 : bias0;
    const unsigned short* Bbase = Wl + (size_t)(wave * 1024 + j0 + ln15) * 2048 + lhi * 8;
    unsigned short* hown = layer ? h1buf : h0buf;

    __shared__ SmemU smem;

    float creg0 = 0.f, creg1 = 0.f;  // private cell state (fixed thread mapping)

    for (int p = 0; p <= T; ++p) {
        const bool act = layer ? (p >= 1) : (p < T);
        if (act) {
            const int t = layer ? (p - 1) : p;
            f32x4 acc0 = {0.f, 0.f, 0.f, 0.f};
            f32x4 acc1 = {0.f, 0.f, 0.f, 0.f};

            if (layer == 0) {
                // issue h-prev staging loads early; hide LLC latency under x-pass
                StageRegs sr;
                stage_issue(sr, h0buf + (size_t)((p + 1) & 1) * 65536 + brow * 1024);

                // ---- pass 0: x-part from seqb (cached) or fp32 seq ----
                if (SEQB) {
                    const unsigned short* a0 = seqb + (size_t)t * 65536 + (size_t)(brow + ln15) * 1024 + lhi * 8;
                    const unsigned short* a1 = a0 + 16 * 1024;
                    const unsigned short* bp = Bbase;
#pragma unroll 4
                    for (int kk = 0; kk < 32; ++kk) {
                        bf16x8 av0 = *((const bf16x8*)a0);
                        bf16x8 av1 = *((const bf16x8*)a1);
                        bf16x8 bv = *((const bf16x8*)bp);
                        acc0 = __builtin_amdgcn_mfma_f32_16x16x32_bf16(av0, bv, acc0, 0, 0, 0);
                        acc1 = __builtin_amdgcn_mfma_f32_16x16x32_bf16(av1, bv, acc1, 0, 0, 0);
                        a0 += 32; a1 += 32; bp += 32;
                    }
                } else {
                    const float* a0f = seq + ((size_t)(brow + ln15) * T + t) * 1024 + lhi * 8;
                    const float* a1f = a0f + (size_t)16 * T * 1024;
                    const unsigned short* bp = Bbase;
#pragma unroll 4
                    for (int kk = 0; kk < 32; ++kk) {
                        float4 l0 = ((const float4*)a0f)[0], h0v = ((const float4*)a0f)[1];
                        float4 l1 = ((const float4*)a1f)[0], h1v = ((const float4*)a1f)[1];
                        bf16x8 av0 = cvt8(l0, h0v), av1 = cvt8(l1, h1v);
                        bf16x8 bv = *((const bf16x8*)bp);
                        acc0 = __builtin_amdgcn_mfma_f32_16x16x32_bf16(av0, bv, acc0, 0, 0, 0);
                        acc1 = __builtin_amdgcn_mfma_f32_16x16x32_bf16(av1, bv, acc1, 0, 0, 0);
                        a0f += 32; a1f += 32; bp += 32;
                    }
                }

                // ---- pass 1: h-part via staged LDS ----
                asm volatile("s_waitcnt vmcnt(0)" ::: "memory");
                __builtin_amdgcn_sched_barrier(0);
                stage_write(sr, smem.a[0]);
                __syncthreads();
                mfma_lds(smem.a[0], Bbase + 1024, acc0, acc1, ln15, lhi);
            } else {
                // issue BOTH h0[t] and h1[t-1] staging loads, one wait
                StageRegs s0, s1;
                stage_issue(s0, h0buf + (size_t)((p - 1) & 1) * 65536 + brow * 1024);
                stage_issue(s1, h1buf + (size_t)(p & 1) * 65536 + brow * 1024);
                asm volatile("s_waitcnt vmcnt(0)" ::: "memory");
                __builtin_amdgcn_sched_barrier(0);
                stage_write(s0, smem.a[0]);
                stage_write(s1, smem.a[1]);
                __syncthreads();
                mfma_lds(smem.a[0], Bbase, acc0, acc1, ln15, lhi);
                mfma_lds(smem.a[1], Bbase + 1024, acc0, acc1, ln15, lhi);
            }

            // ---- epilogue: exchange gates via LDS, update c/h ----
            __syncthreads();  // A-tile reads done before z writes (union)
#pragma unroll
            for (int rr = 0; rr < 4; ++rr) {
                smem.z[wave][4 * lhi + rr][ln15] = acc0[rr];
                smem.z[wave][16 + 4 * lhi + rr][ln15] = acc1[rr];
            }
            __syncthreads();

            const int wout = layer ? ((p + 1) & 1) : (p & 1);
#pragma unroll
            for (int e0 = 0; e0 < 2; ++e0) {
                int e = tid + e0 * 256;
                int bl = e >> 4, jj = e & 15;
                float fz = smem.z[0][bl][jj] + bias[j0 + jj];
                float wz = smem.z[1][bl][jj] + bias[1024 + j0 + jj];
                float iz = smem.z[2][bl][jj] + bias[2048 + j0 + jj];
                float mz = smem.z[3][bl][jj] + bias[3072 + j0 + jj];
                float cold = e0 ? creg1 : creg0;
                float cnew = cold * sigm(fz) + sigm(wz) * tanh_f(iz);
                float h = tanh_f(cnew) * sigm(mz);
                if (e0) creg1 = cnew; else creg0 = cnew;
                int idx = (brow + bl) * 1024 + (j0 + jj);
                __hip_atomic_store(&hown[(size_t)wout * 65536 + idx], f2bf(h),
                                   __ATOMIC_RELAXED, __HIP_MEMORY_SCOPE_AGENT);
                if (layer && p == T) out[idx] = h;
            }
        }

        // ---- distributed-flag grid barrier (no RMW, no cache maintenance) ----
        if (p < T) {
            unsigned int tgt = (unsigned int)(p + 1);
            __syncthreads();  // drains vmcnt: this block's h-stores are at LLC
            if (tid == 0)
                __hip_atomic_store(&flags[bid], tgt, __ATOMIC_RELEASE, __HIP_MEMORY_SCOPE_AGENT);
            for (;;) {
                unsigned int v = __hip_atomic_load(&flags[tid], __ATOMIC_RELAXED,
                                                   __HIP_MEMORY_SCOPE_AGENT);
                if (__syncthreads_and((int)(v >= tgt))) break;
                __builtin_amdgcn_s_sleep(4);
            }
        }
    }
}

// ---------------------------------------------------------------------------
extern "C" void kernel_launch(void* const* d_in, const int* in_sizes, int n_in,
                              void* d_out, int out_size, void* d_ws, size_t ws_size,
                              hipStream_t stream) {
    const float* seq = (const float*)d_in[0];
    const float* Wx0 = (const float*)d_in[1];
    const float* Wh0 = (const float*)d_in[2];
    const float* b0 = (const float*)d_in[3];
    const float* Wx1 = (const float*)d_in[4];
    const float* Wh1 = (const float*)d_in[5];
    const float* b1 = (const float*)d_in[6];
    float* out = (float*)d_out;
    char* ws = (char*)d_ws;
    const int T = 512;

    const size_t WBYTES = (size_t)4096 * 2048 * 2;         // 16.78 MB per layer
    const size_t SEQB_BYTES = (size_t)512 * 64 * 1024 * 2; // 67.1 MB
    const size_t STATE_BYTES = 2 * 262144 + 1024;          // h0[2],h1[2] bf16 + flags

    size_t offSeqb = 2 * WBYTES;
    bool big = ws_size >= 2 * WBYTES + SEQB_BYTES + STATE_BYTES;
    size_t offState = big ? (offSeqb + SEQB_BYTES) : offSeqb;

    unsigned short* W0p = (unsigned short*)(ws);
    unsigned short* W1p = (unsigned short*)(ws + WBYTES);
    unsigned short* seqbp = (unsigned short*)(ws + offSeqb);
    unsigned short* h0p = (unsigned short*)(ws + offState);
    unsigned short* h1p = (unsigned short*)(ws + offState + 262144);
    unsigned int* flagsp = (unsigned int*)(ws + offState + 2 * 262144);

    hipLaunchKernelGGL(cvt_weights, dim3(8192), dim3(256), 0, stream,
                       Wx0, Wh0, Wx1, Wh1, W0p, W1p);
    if (big)
        hipLaunchKernelGGL(cvt_seq, dim3(T * 64), dim3(128), 0, stream, seq, seqbp, T);
    hipMemsetAsync(ws + offState, 0, STATE_BYTES, stream);

    int Tv = T;
    void* args[] = {&seq, &seqbp, &W0p, &W1p, &b0, &b1, &h0p, &h1p, &flagsp, &out, &Tv};
    if (big) {
        hipLaunchCooperativeKernel((void*)lstm_persistent<true>, dim3(256), dim3(256),
                                   args, 0, stream);
    } else {
        hipLaunchCooperativeKernel((void*)lstm_persistent<false>, dim3(256), dim3(256),
                                   args, 0, stream);
    }
}

// Round 4
// 11930.259 us; speedup vs baseline: 2.3956x; 1.0905x over previous
//
#include <hip/hip_runtime.h>

typedef __bf16 bf16x8 __attribute__((ext_vector_type(8)));
typedef float f32x4 __attribute__((ext_vector_type(4)));
typedef unsigned int u32x4 __attribute__((ext_vector_type(4)));

__device__ inline float sigm(float x) { return 1.0f / (1.0f + __expf(-x)); }
__device__ inline float tanh_f(float x) {
    float e = __expf(2.0f * x);
    return 1.0f - 2.0f / (e + 1.0f);
}

__device__ inline unsigned short f2bf(float f) {
    __bf16 h = (__bf16)f;
    return __builtin_bit_cast(unsigned short, h);
}

__device__ inline bf16x8 cvt8(float4 lo, float4 hi) {
    bf16x8 r;
    r[0] = (__bf16)lo.x; r[1] = (__bf16)lo.y; r[2] = (__bf16)lo.z; r[3] = (__bf16)lo.w;
    r[4] = (__bf16)hi.x; r[5] = (__bf16)hi.y; r[6] = (__bf16)hi.z; r[7] = (__bf16)hi.w;
    return r;
}

// --- raw LLC-coherent (L1/L2-bypass) accesses; NO fences, NO cache walks ---
__device__ inline u32x4 ld16_bypass(const unsigned short* p) {
    u32x4 r;
    asm volatile("global_load_dwordx4 %0, %1, off sc0 sc1" : "=v"(r) : "v"(p));
    return r;
}
__device__ inline void st32_cohere(unsigned int* p, unsigned int v) {
    asm volatile("global_store_dword %0, %1, off sc0 sc1" :: "v"(p), "v"(v) : "memory");
}
__device__ inline unsigned int ld32_cohere(const unsigned int* p) {
    unsigned int r;
    asm volatile("global_load_dword %0, %1, off sc0 sc1\n\t"
                 "s_waitcnt vmcnt(0)" : "=v"(r) : "v"(p) : "memory");
    return r;
}

// ---------------------------------------------------------------------------
// Weight conversion: W{x,h}{0,1} fp32 [4096][1024] -> Wcat bf16 [4096][2048]
// ---------------------------------------------------------------------------
__global__ void cvt_weights(const float* __restrict__ Wx0, const float* __restrict__ Wh0,
                            const float* __restrict__ Wx1, const float* __restrict__ Wh1,
                            unsigned short* __restrict__ W0, unsigned short* __restrict__ W1) {
    size_t idx = ((size_t)blockIdx.x * 256 + threadIdx.x) * 8;
    const size_t LSZ = (size_t)4096 * 2048;
    int layer = idx >= LSZ;
    size_t e = idx - (layer ? LSZ : 0);
    int row = (int)(e >> 11);
    int k = (int)(e & 2047);
    const float* src = layer ? (k < 1024 ? Wx1 : Wh1) : (k < 1024 ? Wx0 : Wh0);
    const float* s = src + (size_t)row * 1024 + (k & 1023);
    float4 lo = ((const float4*)s)[0], hi = ((const float4*)s)[1];
    *reinterpret_cast<bf16x8*>((layer ? W1 : W0) + e) = cvt8(lo, hi);
}

// sequence [B][T][I] fp32 -> seqb [T][B][I] bf16
__global__ void cvt_seq(const float* __restrict__ seq, unsigned short* __restrict__ seqb, int T) {
    int t = blockIdx.x >> 6, b = blockIdx.x & 63;
    const float* s = seq + ((size_t)b * T + t) * 1024 + threadIdx.x * 8;
    float4 lo = ((const float4*)s)[0], hi = ((const float4*)s)[1];
    *reinterpret_cast<bf16x8*>(seqb + ((size_t)t * 64 + b) * 1024 + threadIdx.x * 8) = cvt8(lo, hi);
}

// ---------------------------------------------------------------------------
// LDS: two staged A tiles (each 32 x 1024 bf16, 16B slots XOR-swizzled by
// row&7) union'd with the gate-exchange buffer.
// ---------------------------------------------------------------------------
union SmemU {
    unsigned short a[2][32][1024];  // 128 KB
    float z[4][32][16];             // 8 KB
};

struct StageRegs { u32x4 q[16]; };

__device__ inline void stage_issue(StageRegs& r, const unsigned short* __restrict__ src) {
#pragma unroll
    for (int i = 0; i < 16; ++i) {
        int chunk = (int)threadIdx.x + (i << 8);  // 0..4095
        int row = chunk >> 7;                     // 0..31
        int slot = chunk & 127;                   // 16B slot
        r.q[i] = ld16_bypass(src + row * 1024 + slot * 8);
    }
}

__device__ inline void stage_write(const StageRegs& r, unsigned short (&tile)[32][1024]) {
#pragma unroll
    for (int i = 0; i < 16; ++i) {
        int chunk = (int)threadIdx.x + (i << 8);
        int row = chunk >> 7;
        int slot = chunk & 127;
        int sw = slot ^ (row & 7);
        *reinterpret_cast<u32x4*>(&tile[row][sw * 8]) = r.q[i];
    }
}

// MFMA over one K-part (1024 wide) with A from swizzled LDS, B from L2-cached global.
__device__ inline void mfma_lds(const unsigned short (&tile)[32][1024],
                                const unsigned short* __restrict__ bp,
                                f32x4& acc0, f32x4& acc1, int ln15, int lhi) {
#pragma unroll 4
    for (int kk = 0; kk < 32; ++kk) {
        int slot = kk * 4 + lhi;
        int sw = (slot ^ (ln15 & 7)) * 8;
        bf16x8 av0 = *(const bf16x8*)&tile[ln15][sw];
        bf16x8 av1 = *(const bf16x8*)&tile[16 + ln15][sw];
        bf16x8 bv = *((const bf16x8*)(bp + kk * 32));
        acc0 = __builtin_amdgcn_mfma_f32_16x16x32_bf16(av0, bv, acc0, 0, 0, 0);
        acc1 = __builtin_amdgcn_mfma_f32_16x16x32_bf16(av1, bv, acc1, 0, 0, 0);
    }
}

// ---------------------------------------------------------------------------
// Persistent pipelined 2-layer LSTM; distributed-flag grid barrier with
// ZERO release/acquire semantics (no buffer_wbl2 / buffer_inv in the loop).
// Ordering: __syncthreads()'s s_waitcnt vmcnt(0) drains sc0sc1 store-acks
// (LLC-visible) before the flag store issues.
// ---------------------------------------------------------------------------
template <bool SEQB>
__global__ __launch_bounds__(256, 1) void lstm_persistent(
    const float* __restrict__ seq, const unsigned short* __restrict__ seqb,
    const unsigned short* __restrict__ W0, const unsigned short* __restrict__ W1,
    const float* __restrict__ bias0, const float* __restrict__ bias1,
    unsigned short* h0buf, unsigned short* h1buf, unsigned int* flags,
    float* out, int T) {
    const int bid = blockIdx.x;
    const int r = bid & 7, q = bid >> 3;
    const int btile = q & 1, t2 = q >> 1;
    const int layer = t2 >> 3;
    const int jtile = ((t2 & 7) << 3) | r;
    const int j0 = jtile * 16;
    const int brow = btile * 32;

    const int tid = threadIdx.x;
    const int wave = tid >> 6, lane = tid & 63;
    const int ln15 = lane & 15, lhi = lane >> 4;

    const unsigned short* Wl = layer ? W1 : W0;
    const float* bias = layer ? bias1 : bias0;
    const unsigned short* Bbase = Wl + (size_t)(wave * 1024 + j0 + ln15) * 2048 + lhi * 8;
    unsigned short* hown = layer ? h1buf : h0buf;

    __shared__ SmemU smem;

    // epilogue mapping: thread -> (bl, jj), handles jj and jj+1
    const int bl = tid >> 3;
    const int jj = (tid & 7) * 2;
    // hoist bias (constant across phases) into registers
    const float bf0 = bias[j0 + jj],        bf1 = bias[j0 + jj + 1];
    const float bw0 = bias[1024 + j0 + jj], bw1 = bias[1024 + j0 + jj + 1];
    const float bi0 = bias[2048 + j0 + jj], bi1 = bias[2048 + j0 + jj + 1];
    const float bm0 = bias[3072 + j0 + jj], bm1 = bias[3072 + j0 + jj + 1];

    float creg0 = 0.f, creg1 = 0.f;  // private cell state (fixed thread mapping)

    for (int p = 0; p <= T; ++p) {
        const bool act = layer ? (p >= 1) : (p < T);
        if (act) {
            const int t = layer ? (p - 1) : p;
            f32x4 acc0 = {0.f, 0.f, 0.f, 0.f};
            f32x4 acc1 = {0.f, 0.f, 0.f, 0.f};

            if (layer == 0) {
                // issue h-prev staging loads early; hide LLC latency under x-pass
                StageRegs sr;
                stage_issue(sr, h0buf + (size_t)((p + 1) & 1) * 65536 + brow * 1024);

                // ---- pass 0: x-part from seqb (cached) or fp32 seq ----
                if (SEQB) {
                    const unsigned short* a0 = seqb + (size_t)t * 65536 + (size_t)(brow + ln15) * 1024 + lhi * 8;
                    const unsigned short* a1 = a0 + 16 * 1024;
                    const unsigned short* bp = Bbase;
#pragma unroll 4
                    for (int kk = 0; kk < 32; ++kk) {
                        bf16x8 av0 = *((const bf16x8*)a0);
                        bf16x8 av1 = *((const bf16x8*)a1);
                        bf16x8 bv = *((const bf16x8*)bp);
                        acc0 = __builtin_amdgcn_mfma_f32_16x16x32_bf16(av0, bv, acc0, 0, 0, 0);
                        acc1 = __builtin_amdgcn_mfma_f32_16x16x32_bf16(av1, bv, acc1, 0, 0, 0);
                        a0 += 32; a1 += 32; bp += 32;
                    }
                } else {
                    const float* a0f = seq + ((size_t)(brow + ln15) * T + t) * 1024 + lhi * 8;
                    const float* a1f = a0f + (size_t)16 * T * 1024;
                    const unsigned short* bp = Bbase;
#pragma unroll 4
                    for (int kk = 0; kk < 32; ++kk) {
                        float4 l0 = ((const float4*)a0f)[0], h0v = ((const float4*)a0f)[1];
                        float4 l1 = ((const float4*)a1f)[0], h1v = ((const float4*)a1f)[1];
                        bf16x8 av0 = cvt8(l0, h0v), av1 = cvt8(l1, h1v);
                        bf16x8 bv = *((const bf16x8*)bp);
                        acc0 = __builtin_amdgcn_mfma_f32_16x16x32_bf16(av0, bv, acc0, 0, 0, 0);
                        acc1 = __builtin_amdgcn_mfma_f32_16x16x32_bf16(av1, bv, acc1, 0, 0, 0);
                        a0f += 32; a1f += 32; bp += 32;
                    }
                }

                // ---- pass 1: h-part via staged LDS ----
                asm volatile("s_waitcnt vmcnt(0)" ::: "memory");
                __builtin_amdgcn_sched_barrier(0);
                stage_write(sr, smem.a[0]);
                __syncthreads();
                mfma_lds(smem.a[0], Bbase + 1024, acc0, acc1, ln15, lhi);
            } else {
                // issue BOTH h0[t] and h1[t-1] staging loads, one wait
                StageRegs s0, s1;
                stage_issue(s0, h0buf + (size_t)((p - 1) & 1) * 65536 + brow * 1024);
                stage_issue(s1, h1buf + (size_t)(p & 1) * 65536 + brow * 1024);
                asm volatile("s_waitcnt vmcnt(0)" ::: "memory");
                __builtin_amdgcn_sched_barrier(0);
                stage_write(s0, smem.a[0]);
                stage_write(s1, smem.a[1]);
                __syncthreads();
                mfma_lds(smem.a[0], Bbase, acc0, acc1, ln15, lhi);
                mfma_lds(smem.a[1], Bbase + 1024, acc0, acc1, ln15, lhi);
            }

            // ---- epilogue: exchange gates via LDS, update c/h ----
            __syncthreads();  // A-tile reads done before z writes (union)
#pragma unroll
            for (int rr = 0; rr < 4; ++rr) {
                smem.z[wave][4 * lhi + rr][ln15] = acc0[rr];
                smem.z[wave][16 + 4 * lhi + rr][ln15] = acc1[rr];
            }
            __syncthreads();

            {
                float2 zf = *(const float2*)&smem.z[0][bl][jj];
                float2 zw = *(const float2*)&smem.z[1][bl][jj];
                float2 zi = *(const float2*)&smem.z[2][bl][jj];
                float2 zm = *(const float2*)&smem.z[3][bl][jj];
                float c0n = creg0 * sigm(zf.x + bf0) + sigm(zw.x + bw0) * tanh_f(zi.x + bi0);
                float c1n = creg1 * sigm(zf.y + bf1) + sigm(zw.y + bw1) * tanh_f(zi.y + bi1);
                float h0v = tanh_f(c0n) * sigm(zm.x + bm0);
                float h1v = tanh_f(c1n) * sigm(zm.y + bm1);
                creg0 = c0n; creg1 = c1n;
                const int wout = layer ? ((p + 1) & 1) : (p & 1);
                int idx = (brow + bl) * 1024 + (j0 + jj);
                unsigned int packed = (unsigned int)f2bf(h0v) | ((unsigned int)f2bf(h1v) << 16);
                st32_cohere((unsigned int*)&hown[(size_t)wout * 65536 + idx], packed);
                if (layer && p == T) { out[idx] = h0v; out[idx + 1] = h1v; }
            }
        }

        // ---- distributed-flag grid barrier: plain sc0sc1 store + poll ----
        if (p < T) {
            unsigned int tgt = (unsigned int)(p + 1);
            __syncthreads();  // emits s_waitcnt vmcnt(0): h-store acks from LLC done
            if (tid == 0) st32_cohere(&flags[bid], tgt);
            for (;;) {
                unsigned int v = ld32_cohere(&flags[tid]);
                if (__syncthreads_and((int)(v >= tgt))) break;
                __builtin_amdgcn_s_sleep(2);
            }
        }
    }
}

// ---------------------------------------------------------------------------
extern "C" void kernel_launch(void* const* d_in, const int* in_sizes, int n_in,
                              void* d_out, int out_size, void* d_ws, size_t ws_size,
                              hipStream_t stream) {
    const float* seq = (const float*)d_in[0];
    const float* Wx0 = (const float*)d_in[1];
    const float* Wh0 = (const float*)d_in[2];
    const float* b0 = (const float*)d_in[3];
    const float* Wx1 = (const float*)d_in[4];
    const float* Wh1 = (const float*)d_in[5];
    const float* b1 = (const float*)d_in[6];
    float* out = (float*)d_out;
    char* ws = (char*)d_ws;
    const int T = 512;

    const size_t WBYTES = (size_t)4096 * 2048 * 2;         // 16.78 MB per layer
    const size_t SEQB_BYTES = (size_t)512 * 64 * 1024 * 2; // 67.1 MB
    const size_t STATE_BYTES = 2 * 262144 + 1024;          // h0[2],h1[2] bf16 + flags

    size_t offSeqb = 2 * WBYTES;
    bool big = ws_size >= 2 * WBYTES + SEQB_BYTES + STATE_BYTES;
    size_t offState = big ? (offSeqb + SEQB_BYTES) : offSeqb;

    unsigned short* W0p = (unsigned short*)(ws);
    unsigned short* W1p = (unsigned short*)(ws + WBYTES);
    unsigned short* seqbp = (unsigned short*)(ws + offSeqb);
    unsigned short* h0p = (unsigned short*)(ws + offState);
    unsigned short* h1p = (unsigned short*)(ws + offState + 262144);
    unsigned int* flagsp = (unsigned int*)(ws + offState + 2 * 262144);

    hipLaunchKernelGGL(cvt_weights, dim3(8192), dim3(256), 0, stream,
                       Wx0, Wh0, Wx1, Wh1, W0p, W1p);
    if (big)
        hipLaunchKernelGGL(cvt_seq, dim3(T * 64), dim3(128), 0, stream, seq, seqbp, T);
    hipMemsetAsync(ws + offState, 0, STATE_BYTES, stream);

    int Tv = T;
    void* args[] = {&seq, &seqbp, &W0p, &W1p, &b0, &b1, &h0p, &h1p, &flagsp, &out, &Tv};
    if (big) {
        hipLaunchCooperativeKernel((void*)lstm_persistent<true>, dim3(256), dim3(256),
                                   args, 0, stream);
    } else {
        hipLaunchCooperativeKernel((void*)lstm_persistent<false>, dim3(256), dim3(256),
                                   args, 0, stream);
    }
}

// Round 5
// 11485.193 us; speedup vs baseline: 2.4884x; 1.0388x over previous
//
#include <hip/hip_runtime.h>

typedef __bf16 bf16x8 __attribute__((ext_vector_type(8)));
typedef float f32x4 __attribute__((ext_vector_type(4)));
typedef unsigned long long u64;

__device__ inline float sigm(float x) { return 1.0f / (1.0f + __expf(-x)); }
__device__ inline float tanh_f(float x) {
    float e = __expf(2.0f * x);
    return 1.0f - 2.0f / (e + 1.0f);
}

__device__ inline unsigned short f2bf(float f) {
    __bf16 h = (__bf16)f;
    return __builtin_bit_cast(unsigned short, h);
}

__device__ inline bf16x8 cvt8(float4 lo, float4 hi) {
    bf16x8 r;
    r[0] = (__bf16)lo.x; r[1] = (__bf16)lo.y; r[2] = (__bf16)lo.z; r[3] = (__bf16)lo.w;
    r[4] = (__bf16)hi.x; r[5] = (__bf16)hi.y; r[6] = (__bf16)hi.z; r[7] = (__bf16)hi.w;
    return r;
}

// --- compiler-visible LLC-coherent ops: relaxed agent atomics -> sc0 sc1,
// --- no fences, and the compiler's counted vmcnt bookkeeping stays SOUND.
__device__ inline u64 ld64c(const u64* p) {
    return __hip_atomic_load(p, __ATOMIC_RELAXED, __HIP_MEMORY_SCOPE_AGENT);
}
__device__ inline void st32c(unsigned int* p, unsigned int v) {
    __hip_atomic_store(p, v, __ATOMIC_RELAXED, __HIP_MEMORY_SCOPE_AGENT);
}
__device__ inline unsigned int ld32c(const unsigned int* p) {
    return __hip_atomic_load(p, __ATOMIC_RELAXED, __HIP_MEMORY_SCOPE_AGENT);
}

// ---------------------------------------------------------------------------
// Weight conversion: W{x,h}{0,1} fp32 [4096][1024] -> Wcat bf16 [4096][2048]
// ---------------------------------------------------------------------------
__global__ void cvt_weights(const float* __restrict__ Wx0, const float* __restrict__ Wh0,
                            const float* __restrict__ Wx1, const float* __restrict__ Wh1,
                            unsigned short* __restrict__ W0, unsigned short* __restrict__ W1) {
    size_t idx = ((size_t)blockIdx.x * 256 + threadIdx.x) * 8;
    const size_t LSZ = (size_t)4096 * 2048;
    int layer = idx >= LSZ;
    size_t e = idx - (layer ? LSZ : 0);
    int row = (int)(e >> 11);
    int k = (int)(e & 2047);
    const float* src = layer ? (k < 1024 ? Wx1 : Wh1) : (k < 1024 ? Wx0 : Wh0);
    const float* s = src + (size_t)row * 1024 + (k & 1023);
    float4 lo = ((const float4*)s)[0], hi = ((const float4*)s)[1];
    *reinterpret_cast<bf16x8*>((layer ? W1 : W0) + e) = cvt8(lo, hi);
}

// sequence [B][T][I] fp32 -> seqb [T][B][I] bf16
__global__ void cvt_seq(const float* __restrict__ seq, unsigned short* __restrict__ seqb, int T) {
    int t = blockIdx.x >> 6, b = blockIdx.x & 63;
    const float* s = seq + ((size_t)b * T + t) * 1024 + threadIdx.x * 8;
    float4 lo = ((const float4*)s)[0], hi = ((const float4*)s)[1];
    *reinterpret_cast<bf16x8*>(seqb + ((size_t)t * 64 + b) * 1024 + threadIdx.x * 8) = cvt8(lo, hi);
}

// ---------------------------------------------------------------------------
// LDS: two staged A tiles (each 32 x 1024 bf16, 16B slots XOR-swizzled by
// row&7) union'd with the gate-exchange buffer (z aliases a[0] only).
// ---------------------------------------------------------------------------
union SmemU {
    unsigned short a[2][32][1024];  // 128 KB
    float z[4][32][16];             // 8 KB
};

struct StageRegs { u64 q[32]; };

__device__ inline void stage_issue(StageRegs& r, const unsigned short* __restrict__ src) {
#pragma unroll
    for (int i = 0; i < 16; ++i) {
        int chunk = (int)threadIdx.x + (i << 8);  // 0..4095
        int row = chunk >> 7;                     // 0..31
        int slot = chunk & 127;                   // 16B slot
        const u64* s = (const u64*)(src + row * 1024 + slot * 8);
        r.q[2 * i] = ld64c(s);
        r.q[2 * i + 1] = ld64c(s + 1);
    }
}

__device__ inline void stage_write(const StageRegs& r, unsigned short (&tile)[32][1024]) {
#pragma unroll
    for (int i = 0; i < 16; ++i) {
        int chunk = (int)threadIdx.x + (i << 8);
        int row = chunk >> 7;
        int slot = chunk & 127;
        int sw = slot ^ (row & 7);
        u64* d = (u64*)&tile[row][sw * 8];
        d[0] = r.q[2 * i];
        d[1] = r.q[2 * i + 1];
    }
}

// MFMA over one K-part (1024 wide): A from swizzled LDS, B from L2-cached global.
__device__ inline void mfma_lds(const unsigned short (&tile)[32][1024],
                                const unsigned short* __restrict__ bp,
                                f32x4& acc0, f32x4& acc1, int ln15, int lhi) {
#pragma unroll 4
    for (int kk = 0; kk < 32; ++kk) {
        int slot = kk * 4 + lhi;
        int sw = (slot ^ (ln15 & 7)) * 8;
        bf16x8 av0 = *(const bf16x8*)&tile[ln15][sw];
        bf16x8 av1 = *(const bf16x8*)&tile[16 + ln15][sw];
        bf16x8 bv = *((const bf16x8*)(bp + kk * 32));
        acc0 = __builtin_amdgcn_mfma_f32_16x16x32_bf16(av0, bv, acc0, 0, 0, 0);
        acc1 = __builtin_amdgcn_mfma_f32_16x16x32_bf16(av1, bv, acc1, 0, 0, 0);
    }
}

// ---------------------------------------------------------------------------
// Ablation variant 1: barrier-only skeleton (per-phase barrier cost).
// ---------------------------------------------------------------------------
__global__ __launch_bounds__(256, 1) void var_bar(unsigned int* flags, int P) {
    const int tid = threadIdx.x, bid = blockIdx.x;
    for (int p = 0; p < P; ++p) {
        __syncthreads();
        if (tid == 0) st32c(&flags[bid], (unsigned int)(p + 1));
        unsigned int pv = ld32c(&flags[tid]);
        for (;;) {
            if (__syncthreads_and((int)(pv >= (unsigned int)(p + 1)))) break;
            __builtin_amdgcn_s_sleep(2);
            pv = ld32c(&flags[tid]);
        }
    }
}

// ---------------------------------------------------------------------------
// Ablation variant 2: barrier + double h-stage (LLC exchange cost).
// ---------------------------------------------------------------------------
__global__ __launch_bounds__(256, 1) void var_stage(const unsigned short* h0,
                                                    const unsigned short* h1,
                                                    unsigned int* flags,
                                                    unsigned int* sink, int P) {
    __shared__ SmemU smem;
    const int tid = threadIdx.x, bid = blockIdx.x;
    const int brow = (bid & 16) ? 32 : 0;
    for (int p = 0; p < P; ++p) {
        StageRegs s0, s1;
        stage_issue(s0, h0 + (size_t)(p % 3) * 65536 + brow * 1024);
        stage_issue(s1, h1 + (size_t)(p & 1) * 65536 + brow * 1024);
        stage_write(s0, smem.a[0]);
        stage_write(s1, smem.a[1]);
        __syncthreads();
        // keep-alive: impossible condition, compiler can't prove false
        if (ld32c(&flags[tid]) == 0xdeadbeefu)
            sink[tid] = smem.a[0][tid & 31][tid] + smem.a[1][tid & 31][tid + 1];
        __syncthreads();
        if (tid == 0) st32c(&flags[bid], (unsigned int)(p + 1));
        unsigned int pv = ld32c(&flags[tid]);
        for (;;) {
            if (__syncthreads_and((int)(pv >= (unsigned int)(p + 1)))) break;
            __builtin_amdgcn_s_sleep(2);
            pv = ld32c(&flags[tid]);
        }
    }
}

// ---------------------------------------------------------------------------
// Persistent skew-2 pipelined 2-layer LSTM.
// L0 at phase p computes t=p (p<T); L1 computes s=p-2 (2<=p<T+2). P=T+2.
// Phase: [x-pass (no fresh cross-block deps) || early-issued poll] ->
//        h-stage -> h-pass -> epilogue -> flag.  Barrier hides under x-pass.
// h0: 3 rotation buffers (skew WAR safety); h1: 2.
// ---------------------------------------------------------------------------
template <bool SEQB>
__global__ __launch_bounds__(256, 1) void lstm_persistent(
    const float* __restrict__ seq, const unsigned short* __restrict__ seqb,
    const unsigned short* __restrict__ W0, const unsigned short* __restrict__ W1,
    const float* __restrict__ bias0, const float* __restrict__ bias1,
    unsigned short* h0buf, unsigned short* h1buf, unsigned int* flags,
    float* out, int T) {
    const int bid = blockIdx.x;
    const int r = bid & 7, q = bid >> 3;
    const int btile = q & 1, t2 = q >> 1;
    const int layer = t2 >> 3;
    const int jtile = ((t2 & 7) << 3) | r;
    const int j0 = jtile * 16;
    const int brow = btile * 32;

    const int tid = threadIdx.x;
    const int wave = tid >> 6, lane = tid & 63;
    const int ln15 = lane & 15, lhi = lane >> 4;

    const unsigned short* Wl = layer ? W1 : W0;
    const float* bias = layer ? bias1 : bias0;
    const unsigned short* Bbase = Wl + (size_t)(wave * 1024 + j0 + ln15) * 2048 + lhi * 8;
    unsigned short* hown = layer ? h1buf : h0buf;

    __shared__ SmemU smem;

    // epilogue mapping: thread -> (bl, jj), handles jj and jj+1
    const int bl = tid >> 3;
    const int jj = (tid & 7) * 2;
    const float bf0 = bias[j0 + jj],        bf1 = bias[j0 + jj + 1];
    const float bw0 = bias[1024 + j0 + jj], bw1 = bias[1024 + j0 + jj + 1];
    const float bi0 = bias[2048 + j0 + jj], bi1 = bias[2048 + j0 + jj + 1];
    const float bm0 = bias[3072 + j0 + jj], bm1 = bias[3072 + j0 + jj + 1];

    float creg0 = 0.f, creg1 = 0.f;
    const int P = T + 2;

    for (int p = 0; p < P; ++p) {
        const bool act = layer ? (p >= 2) : (p < T);
        const int t = layer ? (p - 2) : p;  // timestep this block processes

        // early-issue the poll load; its value is consumed after the x-pass
        unsigned int pv = 0xFFFFFFFFu;
        if (p > 0) pv = ld32c(&flags[tid]);

        f32x4 acc0 = {0.f, 0.f, 0.f, 0.f};
        f32x4 acc1 = {0.f, 0.f, 0.f, 0.f};

        // ---- x-pass (data confirmed by an earlier barrier; no fresh deps) ----
        if (act) {
            if (layer == 0) {
                if (SEQB) {
                    const unsigned short* a0 = seqb + (size_t)t * 65536 + (size_t)(brow + ln15) * 1024 + lhi * 8;
                    const unsigned short* a1 = a0 + 16 * 1024;
                    const unsigned short* bp = Bbase;
#pragma unroll 4
                    for (int kk = 0; kk < 32; ++kk) {
                        bf16x8 av0 = *((const bf16x8*)a0);
                        bf16x8 av1 = *((const bf16x8*)a1);
                        bf16x8 bv = *((const bf16x8*)bp);
                        acc0 = __builtin_amdgcn_mfma_f32_16x16x32_bf16(av0, bv, acc0, 0, 0, 0);
                        acc1 = __builtin_amdgcn_mfma_f32_16x16x32_bf16(av1, bv, acc1, 0, 0, 0);
                        a0 += 32; a1 += 32; bp += 32;
                    }
                } else {
                    const float* a0f = seq + ((size_t)(brow + ln15) * T + t) * 1024 + lhi * 8;
                    const float* a1f = a0f + (size_t)16 * T * 1024;
                    const unsigned short* bp = Bbase;
#pragma unroll 4
                    for (int kk = 0; kk < 32; ++kk) {
                        float4 l0 = ((const float4*)a0f)[0], h0v = ((const float4*)a0f)[1];
                        float4 l1 = ((const float4*)a1f)[0], h1v = ((const float4*)a1f)[1];
                        bf16x8 av0 = cvt8(l0, h0v), av1 = cvt8(l1, h1v);
                        bf16x8 bv = *((const bf16x8*)bp);
                        acc0 = __builtin_amdgcn_mfma_f32_16x16x32_bf16(av0, bv, acc0, 0, 0, 0);
                        acc1 = __builtin_amdgcn_mfma_f32_16x16x32_bf16(av1, bv, acc1, 0, 0, 0);
                        a0f += 32; a1f += 32; bp += 32;
                    }
                }
            } else {
                // x = h0[t], produced at phase t = p-2, confirmed by poll during p-1
                StageRegs sx;
                stage_issue(sx, h0buf + (size_t)(t % 3) * 65536 + brow * 1024);
                stage_write(sx, smem.a[0]);
                __syncthreads();
                mfma_lds(smem.a[0], Bbase, acc0, acc1, ln15, lhi);
            }
        }

        // ---- resolve barrier for phase p-1 (hidden under the x-pass) ----
        if (p > 0) {
            const unsigned int tgt = (unsigned int)p;
            for (;;) {
                if (__syncthreads_and((int)(pv >= tgt))) break;
                __builtin_amdgcn_s_sleep(2);
                pv = ld32c(&flags[tid]);
            }
        }

        if (act) {
            // ---- h-stage + h-pass (needs phase p-1 results) ----
            const unsigned short* hsrc = layer
                ? h1buf + (size_t)((t - 1) & 1) * 65536 + brow * 1024
                : h0buf + (size_t)((t + 2) % 3) * 65536 + brow * 1024;  // (t-1) mod 3
            StageRegs sh;
            stage_issue(sh, hsrc);
            stage_write(sh, smem.a[1]);
            __syncthreads();
            mfma_lds(smem.a[1], Bbase + 1024, acc0, acc1, ln15, lhi);

            // ---- epilogue: z-exchange (z aliases a[0]; a[0] reads are done) ----
            __syncthreads();  // all h-MFMA LDS reads done before z writes
#pragma unroll
            for (int rr = 0; rr < 4; ++rr) {
                smem.z[wave][4 * lhi + rr][ln15] = acc0[rr];
                smem.z[wave][16 + 4 * lhi + rr][ln15] = acc1[rr];
            }
            __syncthreads();

            {
                float2 zf = *(const float2*)&smem.z[0][bl][jj];
                float2 zw = *(const float2*)&smem.z[1][bl][jj];
                float2 zi = *(const float2*)&smem.z[2][bl][jj];
                float2 zm = *(const float2*)&smem.z[3][bl][jj];
                float c0n = creg0 * sigm(zf.x + bf0) + sigm(zw.x + bw0) * tanh_f(zi.x + bi0);
                float c1n = creg1 * sigm(zf.y + bf1) + sigm(zw.y + bw1) * tanh_f(zi.y + bi1);
                float h0v = tanh_f(c0n) * sigm(zm.x + bm0);
                float h1v = tanh_f(c1n) * sigm(zm.y + bm1);
                creg0 = c0n; creg1 = c1n;
                const int wbuf = layer ? (t & 1) : (t % 3);
                int idx = (brow + bl) * 1024 + (j0 + jj);
                unsigned int packed = (unsigned int)f2bf(h0v) | ((unsigned int)f2bf(h1v) << 16);
                st32c((unsigned int*)&hown[(size_t)wbuf * 65536 + idx], packed);
                if (layer && t == T - 1) { out[idx] = h0v; out[idx + 1] = h1v; }
            }
        }

        // ---- publish phase completion ----
        if (p < P - 1) {
            __syncthreads();  // drains vmcnt: h-stores LLC-visible; also WAR fence
            if (tid == 0) st32c(&flags[bid], (unsigned int)(p + 1));
        }
    }
}

// ---------------------------------------------------------------------------
extern "C" void kernel_launch(void* const* d_in, const int* in_sizes, int n_in,
                              void* d_out, int out_size, void* d_ws, size_t ws_size,
                              hipStream_t stream) {
    const float* seq = (const float*)d_in[0];
    const float* Wx0 = (const float*)d_in[1];
    const float* Wh0 = (const float*)d_in[2];
    const float* b0 = (const float*)d_in[3];
    const float* Wx1 = (const float*)d_in[4];
    const float* Wh1 = (const float*)d_in[5];
    const float* b1 = (const float*)d_in[6];
    float* out = (float*)d_out;
    char* ws = (char*)d_ws;
    const int T = 512;

    const size_t WBYTES = (size_t)4096 * 2048 * 2;         // 16.78 MB per layer
    const size_t SEQB_BYTES = (size_t)512 * 64 * 1024 * 2; // 67.1 MB
    const size_t H0_BYTES = 3 * 131072;
    const size_t H1_BYTES = 2 * 131072;
    const size_t STATE_BYTES = H0_BYTES + H1_BYTES + 2048;  // + flags + sink

    size_t offSeqb = 2 * WBYTES;
    bool big = ws_size >= 2 * WBYTES + SEQB_BYTES + STATE_BYTES;
    size_t offState = big ? (offSeqb + SEQB_BYTES) : offSeqb;

    unsigned short* W0p = (unsigned short*)(ws);
    unsigned short* W1p = (unsigned short*)(ws + WBYTES);
    unsigned short* seqbp = (unsigned short*)(ws + offSeqb);
    unsigned short* h0p = (unsigned short*)(ws + offState);
    unsigned short* h1p = (unsigned short*)(ws + offState + H0_BYTES);
    unsigned int* flagsp = (unsigned int*)(ws + offState + H0_BYTES + H1_BYTES);
    unsigned int* sinkp = (unsigned int*)(ws + offState + H0_BYTES + H1_BYTES + 1024);

    hipLaunchKernelGGL(cvt_weights, dim3(8192), dim3(256), 0, stream,
                       Wx0, Wh0, Wx1, Wh1, W0p, W1p);
    if (big)
        hipLaunchKernelGGL(cvt_seq, dim3(T * 64), dim3(128), 0, stream, seq, seqbp, T);

    // ---- ablation dispatches (diagnosis via per-dispatch rocprof rows) ----
    int Pv = 128;
    hipMemsetAsync(flagsp, 0, 1024, stream);
    {
        void* args[] = {&flagsp, &Pv};
        hipLaunchCooperativeKernel((void*)var_bar, dim3(256), dim3(256), args, 0, stream);
    }
    hipMemsetAsync(flagsp, 0, 1024, stream);
    {
        void* args[] = {&h0p, &h1p, &flagsp, &sinkp, &Pv};
        hipLaunchCooperativeKernel((void*)var_stage, dim3(256), dim3(256), args, 0, stream);
    }

    // ---- real run ----
    hipMemsetAsync(ws + offState, 0, STATE_BYTES, stream);
    int Tv = T;
    void* args[] = {&seq, &seqbp, &W0p, &W1p, &b0, &b1, &h0p, &h1p, &flagsp, &out, &Tv};
    if (big) {
        hipLaunchCooperativeKernel((void*)lstm_persistent<true>, dim3(256), dim3(256),
                                   args, 0, stream);
    } else {
        hipLaunchCooperativeKernel((void*)lstm_persistent<false>, dim3(256), dim3(256),
                                   args, 0, stream);
    }
}

// Round 7
// 7583.854 us; speedup vs baseline: 3.7685x; 1.5144x over previous
//
#include <hip/hip_runtime.h>

typedef __bf16 bf16x8 __attribute__((ext_vector_type(8)));
typedef float f32x4 __attribute__((ext_vector_type(4)));
typedef unsigned long long u64;

__device__ inline float sigm(float x) { return 1.0f / (1.0f + __expf(-x)); }
__device__ inline float tanh_f(float x) {
    float e = __expf(2.0f * x);
    return 1.0f - 2.0f / (e + 1.0f);
}

__device__ inline unsigned short f2bf(float f) {
    __bf16 h = (__bf16)f;
    return __builtin_bit_cast(unsigned short, h);
}

__device__ inline bf16x8 cvt8(float4 lo, float4 hi) {
    bf16x8 r;
    r[0] = (__bf16)lo.x; r[1] = (__bf16)lo.y; r[2] = (__bf16)lo.z; r[3] = (__bf16)lo.w;
    r[4] = (__bf16)hi.x; r[5] = (__bf16)hi.y; r[6] = (__bf16)hi.z; r[7] = (__bf16)hi.w;
    return r;
}

// compiler-visible LLC-coherent ops (sc0 sc1, no fences, counted vmcnt)
__device__ inline u64 ld64c(const u64* p) {
    return __hip_atomic_load(p, __ATOMIC_RELAXED, __HIP_MEMORY_SCOPE_AGENT);
}
__device__ inline void st32c(unsigned int* p, unsigned int v) {
    __hip_atomic_store(p, v, __ATOMIC_RELAXED, __HIP_MEMORY_SCOPE_AGENT);
}
__device__ inline unsigned int ld32c(const unsigned int* p) {
    return __hip_atomic_load(p, __ATOMIC_RELAXED, __HIP_MEMORY_SCOPE_AGENT);
}

// ---------------------------------------------------------------------------
// Weight conversion: W{x,h}{0,1} fp32 [4096][1024] -> Wcat bf16 [4096][2048]
// ---------------------------------------------------------------------------
__global__ void cvt_weights(const float* __restrict__ Wx0, const float* __restrict__ Wh0,
                            const float* __restrict__ Wx1, const float* __restrict__ Wh1,
                            unsigned short* __restrict__ W0, unsigned short* __restrict__ W1) {
    size_t idx = ((size_t)blockIdx.x * 256 + threadIdx.x) * 8;
    const size_t LSZ = (size_t)4096 * 2048;
    int layer = idx >= LSZ;
    size_t e = idx - (layer ? LSZ : 0);
    int row = (int)(e >> 11);
    int k = (int)(e & 2047);
    const float* src = layer ? (k < 1024 ? Wx1 : Wh1) : (k < 1024 ? Wx0 : Wh0);
    const float* s = src + (size_t)row * 1024 + (k & 1023);
    float4 lo = ((const float4*)s)[0], hi = ((const float4*)s)[1];
    *reinterpret_cast<bf16x8*>((layer ? W1 : W0) + e) = cvt8(lo, hi);
}

// sequence [B][T][I] fp32 -> seqb [T][B][I] bf16
__global__ void cvt_seq(const float* __restrict__ seq, unsigned short* __restrict__ seqb, int T) {
    int t = blockIdx.x >> 6, b = blockIdx.x & 63;
    const float* s = seq + ((size_t)b * T + t) * 1024 + threadIdx.x * 8;
    float4 lo = ((const float4*)s)[0], hi = ((const float4*)s)[1];
    *reinterpret_cast<bf16x8*>(seqb + ((size_t)t * 64 + b) * 1024 + threadIdx.x * 8) = cvt8(lo, hi);
}

// ---------------------------------------------------------------------------
// LDS: two staged A tiles (32 x 1024 bf16 each, 16B slots XOR-swizzled by
// row&7); z-exchange aliases tile a[0] (safe: separated by syncs).
// ---------------------------------------------------------------------------
union SmemU {
    unsigned short a[2][32][1024];  // 128 KB
    float z[4][32][16];             // 8 KB (aliases a[0])
};

struct StageRegs { u64 q[32]; };

__device__ inline void stage_issue(StageRegs& r, const unsigned short* __restrict__ src) {
#pragma unroll
    for (int i = 0; i < 16; ++i) {
        int chunk = (int)threadIdx.x + (i << 8);  // 0..4095
        int row = chunk >> 7;                     // 0..31
        int slot = chunk & 127;                   // 16B slot
        const u64* s = (const u64*)(src + row * 1024 + slot * 8);
        r.q[2 * i] = ld64c(s);
        r.q[2 * i + 1] = ld64c(s + 1);
    }
}

// plain cached loads (seqb is read-only after cvt_seq; runtime handles coherence)
__device__ inline void stage_issue_plain(StageRegs& r, const unsigned short* __restrict__ src) {
#pragma unroll
    for (int i = 0; i < 16; ++i) {
        int chunk = (int)threadIdx.x + (i << 8);
        int row = chunk >> 7;
        int slot = chunk & 127;
        const u64* s = (const u64*)(src + row * 1024 + slot * 8);
        r.q[2 * i] = s[0];
        r.q[2 * i + 1] = s[1];
    }
}

__device__ inline void stage_write(const StageRegs& r, unsigned short (&tile)[32][1024]) {
#pragma unroll
    for (int i = 0; i < 16; ++i) {
        int chunk = (int)threadIdx.x + (i << 8);
        int row = chunk >> 7;
        int slot = chunk & 127;
        int sw = slot ^ (row & 7);
        u64* d = (u64*)&tile[row][sw * 8];
        d[0] = r.q[2 * i];
        d[1] = r.q[2 * i + 1];
    }
}

// MFMA K=1024 pass: A from swizzled LDS, B streamed from L2-resident weights.
__device__ inline void mfma_bstream(const unsigned short (&tile)[32][1024],
                                    const unsigned short* __restrict__ bp,
                                    f32x4& acc0, f32x4& acc1, int ln15, int lhi) {
#pragma unroll
    for (int kk = 0; kk < 32; ++kk) {
        int sw = (((kk << 2) + lhi) ^ (ln15 & 7)) * 8;
        bf16x8 av0 = *(const bf16x8*)&tile[ln15][sw];
        bf16x8 av1 = *(const bf16x8*)&tile[16 + ln15][sw];
        bf16x8 bv = *((const bf16x8*)(bp + kk * 32));
        acc0 = __builtin_amdgcn_mfma_f32_16x16x32_bf16(av0, bv, acc0, 0, 0, 0);
        acc1 = __builtin_amdgcn_mfma_f32_16x16x32_bf16(av1, bv, acc1, 0, 0, 0);
    }
}

// MFMA K=1024 pass: A from swizzled LDS, B from persistent registers (h-part).
__device__ inline void mfma_wreg(const unsigned short (&tile)[32][1024],
                                 const bf16x8 (&w)[32],
                                 f32x4& acc0, f32x4& acc1, int ln15, int lhi) {
#pragma unroll
    for (int kk = 0; kk < 32; ++kk) {
        int sw = (((kk << 2) + lhi) ^ (ln15 & 7)) * 8;
        bf16x8 av0 = *(const bf16x8*)&tile[ln15][sw];
        bf16x8 av1 = *(const bf16x8*)&tile[16 + ln15][sw];
        acc0 = __builtin_amdgcn_mfma_f32_16x16x32_bf16(av0, w[kk], acc0, 0, 0, 0);
        acc1 = __builtin_amdgcn_mfma_f32_16x16x32_bf16(av1, w[kk], acc1, 0, 0, 0);
    }
}

// ---------------------------------------------------------------------------
// Persistent skew-2 pipelined 2-layer LSTM.
// h-part weights register-resident (128 VGPR/lane); x-part weights streamed
// from L2 (per-XCD x-working-set 2MB < 4MB L2 -> resident).
// L0 at phase p computes t=p (p<T); L1 computes t=p-2. P=T+2.
// ---------------------------------------------------------------------------
template <bool SEQB>
__global__ __launch_bounds__(256, 1) void lstm_persistent(
    const float* __restrict__ seq, const unsigned short* __restrict__ seqb,
    const unsigned short* __restrict__ W0, const unsigned short* __restrict__ W1,
    const float* __restrict__ bias0, const float* __restrict__ bias1,
    unsigned short* h0buf, unsigned short* h1buf, unsigned int* flags,
    float* out, int T) {
    const int bid = blockIdx.x;
    const int r = bid & 7, q = bid >> 3;
    const int btile = q & 1, t2 = q >> 1;
    const int layer = t2 >> 3;
    const int jtile = ((t2 & 7) << 3) | r;
    const int j0 = jtile * 16;
    const int brow = btile * 32;

    const int tid = threadIdx.x;
    const int wave = tid >> 6, lane = tid & 63;
    const int ln15 = lane & 15, lhi = lane >> 4;

    const unsigned short* Wl = layer ? W1 : W0;
    const float* bias = layer ? bias1 : bias0;
    const unsigned short* Bbase = Wl + (size_t)(wave * 1024 + j0 + ln15) * 2048 + lhi * 8;
    unsigned short* hown = layer ? h1buf : h0buf;

    __shared__ SmemU smem;

    // ---- persistent h-part weights: 32 x bf16x8 = 128 VGPRs per lane ----
    bf16x8 wreg[32];
#pragma unroll
    for (int q2 = 0; q2 < 32; ++q2)
        wreg[q2] = *reinterpret_cast<const bf16x8*>(Bbase + 1024 + q2 * 32);

    // epilogue mapping: thread -> (bl, jj), handles jj and jj+1
    const int bl = tid >> 3;
    const int jj = (tid & 7) * 2;
    const float bf0 = bias[j0 + jj],        bf1 = bias[j0 + jj + 1];
    const float bw0 = bias[1024 + j0 + jj], bw1 = bias[1024 + j0 + jj + 1];
    const float bi0 = bias[2048 + j0 + jj], bi1 = bias[2048 + j0 + jj + 1];
    const float bm0 = bias[3072 + j0 + jj], bm1 = bias[3072 + j0 + jj + 1];

    float creg0 = 0.f, creg1 = 0.f;
    const int P = T + 2;

    for (int p = 0; p < P; ++p) {
        const bool act = layer ? (p >= 2) : (p < T);
        const int t = layer ? (p - 2) : p;

        // ---- stage0: x-input tile (no fresh cross-block dependency) ----
        StageRegs s0;
        if (act) {
            if (layer == 0) {
                if (SEQB)
                    stage_issue_plain(s0, seqb + (size_t)t * 65536 + brow * 1024);
            } else {
                // h0[t]: written at phase t=p-2, confirmed by the poll at p-1
                stage_issue(s0, h0buf + (size_t)(t % 3) * 65536 + brow * 1024);
            }
        }

        // early-issue the poll load; consumed at the resolve point
        unsigned int pv = 0xFFFFFFFFu;
        if (p > 0) pv = ld32c(&flags[tid]);

        if (act && (layer == 1 || SEQB)) {
            stage_write(s0, smem.a[0]);
            __syncthreads();
        }

        // ---- resolve barrier for phase p-1 ----
        if (p > 0) {
            const unsigned int tgt = (unsigned int)p;
            for (;;) {
                if (__syncthreads_and((int)(pv >= tgt))) break;
                __builtin_amdgcn_s_sleep(2);
                pv = ld32c(&flags[tid]);
            }
        }

        if (act) {
            f32x4 acc0 = {0.f, 0.f, 0.f, 0.f};
            f32x4 acc1 = {0.f, 0.f, 0.f, 0.f};

            // ---- stage1 issue: own-layer h-prev (needs phase p-1 results) ----
            StageRegs s1;
            const unsigned short* hsrc = layer
                ? h1buf + (size_t)((t + 1) & 1) * 65536 + brow * 1024    // h1[t-1]
                : h0buf + (size_t)((t + 2) % 3) * 65536 + brow * 1024;   // h0[t-1]
            stage_issue(s1, hsrc);

            // ---- pass 0: x-part, B streamed from L2 (covers stage1 latency) ----
            if (layer == 0 && !SEQB) {
                const float* a0f = seq + ((size_t)(brow + ln15) * T + t) * 1024 + lhi * 8;
                const float* a1f = a0f + (size_t)16 * T * 1024;
                const unsigned short* bp = Bbase;
#pragma unroll
                for (int kk = 0; kk < 32; ++kk) {
                    float4 l0 = ((const float4*)a0f)[0], h0v = ((const float4*)a0f)[1];
                    float4 l1 = ((const float4*)a1f)[0], h1v = ((const float4*)a1f)[1];
                    bf16x8 av0 = cvt8(l0, h0v), av1 = cvt8(l1, h1v);
                    bf16x8 bv = *((const bf16x8*)bp);
                    acc0 = __builtin_amdgcn_mfma_f32_16x16x32_bf16(av0, bv, acc0, 0, 0, 0);
                    acc1 = __builtin_amdgcn_mfma_f32_16x16x32_bf16(av1, bv, acc1, 0, 0, 0);
                    a0f += 32; a1f += 32; bp += 32;
                }
            } else {
                mfma_bstream(smem.a[0], Bbase, acc0, acc1, ln15, lhi);
            }

            // ---- pass 1: h-part with register-resident B ----
            stage_write(s1, smem.a[1]);
            __syncthreads();
            mfma_wreg(smem.a[1], wreg, acc0, acc1, ln15, lhi);

            // ---- epilogue: z-exchange (z aliases a[0]; its reads are done) ----
#pragma unroll
            for (int rr = 0; rr < 4; ++rr) {
                smem.z[wave][4 * lhi + rr][ln15] = acc0[rr];
                smem.z[wave][16 + 4 * lhi + rr][ln15] = acc1[rr];
            }
            __syncthreads();

            {
                float2 zf = *(const float2*)&smem.z[0][bl][jj];
                float2 zw = *(const float2*)&smem.z[1][bl][jj];
                float2 zi = *(const float2*)&smem.z[2][bl][jj];
                float2 zm = *(const float2*)&smem.z[3][bl][jj];
                float c0n = creg0 * sigm(zf.x + bf0) + sigm(zw.x + bw0) * tanh_f(zi.x + bi0);
                float c1n = creg1 * sigm(zf.y + bf1) + sigm(zw.y + bw1) * tanh_f(zi.y + bi1);
                float h0v = tanh_f(c0n) * sigm(zm.x + bm0);
                float h1v = tanh_f(c1n) * sigm(zm.y + bm1);
                creg0 = c0n; creg1 = c1n;
                const int wbuf = layer ? (t & 1) : (t % 3);
                int idx = (brow + bl) * 1024 + (j0 + jj);
                unsigned int packed = (unsigned int)f2bf(h0v) | ((unsigned int)f2bf(h1v) << 16);
                st32c((unsigned int*)&hown[(size_t)wbuf * 65536 + idx], packed);
                if (layer && t == T - 1) { out[idx] = h0v; out[idx + 1] = h1v; }
            }
        }

        // ---- publish phase completion ----
        if (p < P - 1) {
            __syncthreads();  // drains vmcnt: h-stores LLC-visible; WAR fence for a[0]/z
            if (tid == 0) st32c(&flags[bid], (unsigned int)(p + 1));
        }
    }
}

// ---------------------------------------------------------------------------
extern "C" void kernel_launch(void* const* d_in, const int* in_sizes, int n_in,
                              void* d_out, int out_size, void* d_ws, size_t ws_size,
                              hipStream_t stream) {
    const float* seq = (const float*)d_in[0];
    const float* Wx0 = (const float*)d_in[1];
    const float* Wh0 = (const float*)d_in[2];
    const float* b0 = (const float*)d_in[3];
    const float* Wx1 = (const float*)d_in[4];
    const float* Wh1 = (const float*)d_in[5];
    const float* b1 = (const float*)d_in[6];
    float* out = (float*)d_out;
    char* ws = (char*)d_ws;
    const int T = 512;

    const size_t WBYTES = (size_t)4096 * 2048 * 2;         // 16.78 MB per layer
    const size_t SEQB_BYTES = (size_t)512 * 64 * 1024 * 2; // 67.1 MB
    const size_t H0_BYTES = 3 * 131072;
    const size_t H1_BYTES = 2 * 131072;
    const size_t STATE_BYTES = H0_BYTES + H1_BYTES + 1024;  // + flags

    size_t offSeqb = 2 * WBYTES;
    bool big = ws_size >= 2 * WBYTES + SEQB_BYTES + STATE_BYTES;
    size_t offState = big ? (offSeqb + SEQB_BYTES) : offSeqb;

    unsigned short* W0p = (unsigned short*)(ws);
    unsigned short* W1p = (unsigned short*)(ws + WBYTES);
    unsigned short* seqbp = (unsigned short*)(ws + offSeqb);
    unsigned short* h0p = (unsigned short*)(ws + offState);
    unsigned short* h1p = (unsigned short*)(ws + offState + H0_BYTES);
    unsigned int* flagsp = (unsigned int*)(ws + offState + H0_BYTES + H1_BYTES);

    hipLaunchKernelGGL(cvt_weights, dim3(8192), dim3(256), 0, stream,
                       Wx0, Wh0, Wx1, Wh1, W0p, W1p);
    if (big)
        hipLaunchKernelGGL(cvt_seq, dim3(T * 64), dim3(128), 0, stream, seq, seqbp, T);
    hipMemsetAsync(ws + offState, 0, STATE_BYTES, stream);

    int Tv = T;
    void* args[] = {&seq, &seqbp, &W0p, &W1p, &b0, &b1, &h0p, &h1p, &flagsp, &out, &Tv};
    if (big) {
        hipError_t e = hipLaunchCooperativeKernel((void*)lstm_persistent<true>,
                                                  dim3(256), dim3(256), args, 0, stream);
        if (e != hipSuccess) {
            // co-residency is guaranteed by capacity (1 block/CU, 256 blocks);
            // the custom flag barrier needs no cooperative-launch semantics.
            hipLaunchKernelGGL((lstm_persistent<true>), dim3(256), dim3(256), 0, stream,
                               seq, seqbp, W0p, W1p, b0, b1, h0p, h1p, flagsp, out, Tv);
        }
    } else {
        hipError_t e = hipLaunchCooperativeKernel((void*)lstm_persistent<false>,
                                                  dim3(256), dim3(256), args, 0, stream);
        if (e != hipSuccess) {
            hipLaunchKernelGGL((lstm_persistent<false>), dim3(256), dim3(256), 0, stream,
                               seq, seqbp, W0p, W1p, b0, b1, h0p, h1p, flagsp, out, Tv);
        }
    }
}

// Round 8
// 4007.261 us; speedup vs baseline: 7.1320x; 1.8925x over previous
//
#include <hip/hip_runtime.h>

typedef __bf16 bf16x8 __attribute__((ext_vector_type(8)));
typedef float f32x4 __attribute__((ext_vector_type(4)));
typedef unsigned long long u64;

__device__ inline float sigm(float x) { return 1.0f / (1.0f + __expf(-x)); }
__device__ inline float tanh_f(float x) {
    float e = __expf(2.0f * x);
    return 1.0f - 2.0f / (e + 1.0f);
}

__device__ inline unsigned short f2bf(float f) {
    __bf16 h = (__bf16)f;
    return __builtin_bit_cast(unsigned short, h);
}

__device__ inline bf16x8 cvt8(float4 lo, float4 hi) {
    bf16x8 r;
    r[0] = (__bf16)lo.x; r[1] = (__bf16)lo.y; r[2] = (__bf16)lo.z; r[3] = (__bf16)lo.w;
    r[4] = (__bf16)hi.x; r[5] = (__bf16)hi.y; r[6] = (__bf16)hi.z; r[7] = (__bf16)hi.w;
    return r;
}

// compiler-visible LLC-coherent ops (sc0 sc1, no fences, counted vmcnt)
__device__ inline u64 ld64c(const u64* p) {
    return __hip_atomic_load(p, __ATOMIC_RELAXED, __HIP_MEMORY_SCOPE_AGENT);
}
__device__ inline void st32c(unsigned int* p, unsigned int v) {
    __hip_atomic_store(p, v, __ATOMIC_RELAXED, __HIP_MEMORY_SCOPE_AGENT);
}
__device__ inline unsigned int ld32c(const unsigned int* p) {
    return __hip_atomic_load(p, __ATOMIC_RELAXED, __HIP_MEMORY_SCOPE_AGENT);
}

// ---------------------------------------------------------------------------
// FRAGMENT-MAJOR tile format for all 32x1024 bf16 A-tiles (h and seqb):
//   u16 offset F(row, col) = (row>>4)*16384 + (col>>5)*512
//                          + (((col>>3)&3)*16 + (row&15))*8 + (col&7)
// Consumers copy tiles LINEARLY (coalesced 16B/lane) and MFMA-read linearly
// (tile + kk*512 + lane*8) -> zero LDS bank conflicts by construction.
// ---------------------------------------------------------------------------

// Weight conversion: W{x,h}{0,1} fp32 [4096][1024] -> Wcat bf16 [4096][2048]
__global__ void cvt_weights(const float* __restrict__ Wx0, const float* __restrict__ Wh0,
                            const float* __restrict__ Wx1, const float* __restrict__ Wh1,
                            unsigned short* __restrict__ W0, unsigned short* __restrict__ W1) {
    size_t idx = ((size_t)blockIdx.x * 256 + threadIdx.x) * 8;
    const size_t LSZ = (size_t)4096 * 2048;
    int layer = idx >= LSZ;
    size_t e = idx - (layer ? LSZ : 0);
    int row = (int)(e >> 11);
    int k = (int)(e & 2047);
    const float* src = layer ? (k < 1024 ? Wx1 : Wh1) : (k < 1024 ? Wx0 : Wh0);
    const float* s = src + (size_t)row * 1024 + (k & 1023);
    float4 lo = ((const float4*)s)[0], hi = ((const float4*)s)[1];
    *reinterpret_cast<bf16x8*>((layer ? W1 : W0) + e) = cvt8(lo, hi);
}

// sequence [B][T][I] fp32 -> seqb [T][btile][fragment-major 32x1024 tile] bf16
__global__ void cvt_seq(const float* __restrict__ seq, unsigned short* __restrict__ seqb, int T) {
    int t = blockIdx.x >> 6, b = blockIdx.x & 63;
    int row = b & 31, btile = b >> 5, tid = threadIdx.x;  // 128 threads, 8 cols each
    const float* s = seq + ((size_t)b * T + t) * 1024 + tid * 8;
    float4 lo = ((const float4*)s)[0], hi = ((const float4*)s)[1];
    int off = ((row >> 4) << 14) + ((tid >> 2) << 9) + (((tid & 3) << 4) + (row & 15)) * 8;
    *reinterpret_cast<bf16x8*>(seqb + ((size_t)t * 2 + btile) * 32768 + off) = cvt8(lo, hi);
}

// ---------------------------------------------------------------------------
// LDS: two A tiles (64 KB each, fragment-major, linear);
// z-exchange aliases tile a[0] (separated by syncs).
// ---------------------------------------------------------------------------
union SmemU {
    unsigned short a[2][32768];  // 128 KB
    float z[4][32][16];          // 8 KB (aliases a[0])
};

struct StageRegs { u64 q[32]; };  // 64 VGPRs, only one live at a time

__device__ inline void stage_issue(StageRegs& r, const unsigned short* __restrict__ src) {
#pragma unroll
    for (int i = 0; i < 16; ++i) {
        const u64* s = (const u64*)(src + (size_t)((threadIdx.x + (i << 8)) << 3));
        r.q[2 * i] = ld64c(s);
        r.q[2 * i + 1] = ld64c(s + 1);
    }
}

__device__ inline void stage_issue_plain(StageRegs& r, const unsigned short* __restrict__ src) {
#pragma unroll
    for (int i = 0; i < 16; ++i) {
        const u64* s = (const u64*)(src + (size_t)((threadIdx.x + (i << 8)) << 3));
        r.q[2 * i] = s[0];
        r.q[2 * i + 1] = s[1];
    }
}

__device__ inline void stage_write(const StageRegs& r, unsigned short* tile) {
#pragma unroll
    for (int i = 0; i < 16; ++i) {
        u64* d = (u64*)(tile + (size_t)((threadIdx.x + (i << 8)) << 3));
        d[0] = r.q[2 * i];
        d[1] = r.q[2 * i + 1];
    }
}

// MFMA K=1024 pass: A linear fragment-major LDS, B from persistent registers.
template <int BASE>
__device__ inline void mfma_pass(const unsigned short* tile, const bf16x8 (&w)[64],
                                 f32x4& acc0, f32x4& acc1, int lane) {
#pragma unroll
    for (int kk = 0; kk < 32; ++kk) {
        bf16x8 av0 = *(const bf16x8*)(tile + kk * 512 + lane * 8);
        bf16x8 av1 = *(const bf16x8*)(tile + 16384 + kk * 512 + lane * 8);
        acc0 = __builtin_amdgcn_mfma_f32_16x16x32_bf16(av0, w[BASE + kk], acc0, 0, 0, 0);
        acc1 = __builtin_amdgcn_mfma_f32_16x16x32_bf16(av1, w[BASE + kk], acc1, 0, 0, 0);
    }
}

// ---------------------------------------------------------------------------
// Persistent skew-2 pipelined 2-layer LSTM, FULL weight panel in registers
// (wreg[64] = 256 VGPR/lane = 256 KB/block): zero weight traffic per phase.
// L0 at phase p computes t=p (p<T); L1 computes t=p-2. P=T+2.
// ---------------------------------------------------------------------------
template <bool SEQB>
__global__ __launch_bounds__(256, 1) void lstm_persistent(
    const float* __restrict__ seq, const unsigned short* __restrict__ seqb,
    const unsigned short* __restrict__ W0, const unsigned short* __restrict__ W1,
    const float* __restrict__ bias0, const float* __restrict__ bias1,
    unsigned short* h0buf, unsigned short* h1buf, unsigned int* flags,
    float* out, int T) {
    const int bid = blockIdx.x;
    const int r = bid & 7, q = bid >> 3;
    const int btile = q & 1, t2 = q >> 1;
    const int layer = t2 >> 3;
    const int jtile = ((t2 & 7) << 3) | r;
    const int j0 = jtile * 16;
    const int brow = btile * 32;

    const int tid = threadIdx.x;
    const int wave = tid >> 6, lane = tid & 63;
    const int ln15 = lane & 15, lhi = lane >> 4;

    const unsigned short* Wl = layer ? W1 : W0;
    const float* bias = layer ? bias1 : bias0;
    const unsigned short* Bbase = Wl + (size_t)(wave * 1024 + j0 + ln15) * 2048 + lhi * 8;
    unsigned short* hown = layer ? h1buf : h0buf;

    __shared__ SmemU smem;

    // ---- persistent weight panel: 64 x bf16x8 = 256 VGPRs per lane ----
    bf16x8 wreg[64];
#pragma unroll
    for (int q2 = 0; q2 < 64; ++q2)
        wreg[q2] = *reinterpret_cast<const bf16x8*>(Bbase + q2 * 32);

    // epilogue mapping: thread -> (bl, jj), handles cols jj, jj+1
    const int bl = tid >> 3;
    const int jj = (tid & 7) * 2;
    const float bf0 = bias[j0 + jj],        bf1 = bias[j0 + jj + 1];
    const float bw0 = bias[1024 + j0 + jj], bw1 = bias[1024 + j0 + jj + 1];
    const float bi0 = bias[2048 + j0 + jj], bi1 = bias[2048 + j0 + jj + 1];
    const float bm0 = bias[3072 + j0 + jj], bm1 = bias[3072 + j0 + jj + 1];
    // fragment-major u16 offset within the destination h-tile
    const int colg = j0 + jj;
    const int hoff = ((bl >> 4) << 14) + ((colg >> 5) << 9) +
                     ((((colg >> 3) & 3) << 4) + (bl & 15)) * 8 + (colg & 7);

    float creg0 = 0.f, creg1 = 0.f;
    const int P = T + 2;

    for (int p = 0; p < P; ++p) {
        const bool act = layer ? (p >= 2) : (p < T);
        const int t = layer ? (p - 2) : p;

        // ---- stage0: x-input tile (confirmed by an earlier poll) ----
        {
            StageRegs s0;
            bool have0 = false;
            if (act) {
                if (layer == 0) {
                    if (SEQB) {
                        stage_issue_plain(s0, seqb + ((size_t)t * 2 + btile) * 32768);
                        have0 = true;
                    }
                } else {
                    stage_issue(s0, h0buf + (size_t)((t % 3) * 2 + btile) * 32768);
                    have0 = true;
                }
            }
            if (have0) {
                stage_write(s0, smem.a[0]);
                __syncthreads();
            }
        }

        // early-issue the poll load; consumed at the resolve point
        unsigned int pv = 0xFFFFFFFFu;
        if (p > 0) pv = ld32c(&flags[tid]);

        // ---- resolve barrier for phase p-1 ----
        if (p > 0) {
            const unsigned int tgt = (unsigned int)p;
            for (;;) {
                if (__syncthreads_and((int)(pv >= tgt))) break;
                __builtin_amdgcn_s_sleep(2);
                pv = ld32c(&flags[tid]);
            }
        }

        if (act) {
            f32x4 acc0 = {0.f, 0.f, 0.f, 0.f};
            f32x4 acc1 = {0.f, 0.f, 0.f, 0.f};

            // ---- stage1 issue: own-layer h-prev (needs phase p-1 results) ----
            StageRegs s1;
            const unsigned short* hsrc = layer
                ? h1buf + (size_t)(((t + 1) & 1) * 2 + btile) * 32768   // h1[t-1]
                : h0buf + (size_t)(((t + 2) % 3) * 2 + btile) * 32768;  // h0[t-1]
            stage_issue(s1, hsrc);

            // ---- pass 0: x-part (covers stage1 latency) ----
            if (layer == 0 && !SEQB) {
                const float* a0f = seq + ((size_t)(brow + ln15) * T + t) * 1024 + lhi * 8;
                const float* a1f = a0f + (size_t)16 * T * 1024;
#pragma unroll
                for (int kk = 0; kk < 32; ++kk) {
                    float4 l0 = ((const float4*)a0f)[0], h0v = ((const float4*)a0f)[1];
                    float4 l1 = ((const float4*)a1f)[0], h1v = ((const float4*)a1f)[1];
                    bf16x8 av0 = cvt8(l0, h0v), av1 = cvt8(l1, h1v);
                    acc0 = __builtin_amdgcn_mfma_f32_16x16x32_bf16(av0, wreg[kk], acc0, 0, 0, 0);
                    acc1 = __builtin_amdgcn_mfma_f32_16x16x32_bf16(av1, wreg[kk], acc1, 0, 0, 0);
                    a0f += 32; a1f += 32;
                }
            } else {
                mfma_pass<0>(smem.a[0], wreg, acc0, acc1, lane);
            }

            // ---- pass 1: h-part ----
            stage_write(s1, smem.a[1]);
            __syncthreads();
            mfma_pass<32>(smem.a[1], wreg, acc0, acc1, lane);

            // ---- epilogue: z-exchange (z aliases a[0]; its reads are done) ----
#pragma unroll
            for (int rr = 0; rr < 4; ++rr) {
                smem.z[wave][4 * lhi + rr][ln15] = acc0[rr];
                smem.z[wave][16 + 4 * lhi + rr][ln15] = acc1[rr];
            }
            __syncthreads();

            {
                float2 zf = *(const float2*)&smem.z[0][bl][jj];
                float2 zw = *(const float2*)&smem.z[1][bl][jj];
                float2 zi = *(const float2*)&smem.z[2][bl][jj];
                float2 zm = *(const float2*)&smem.z[3][bl][jj];
                float c0n = creg0 * sigm(zf.x + bf0) + sigm(zw.x + bw0) * tanh_f(zi.x + bi0);
                float c1n = creg1 * sigm(zf.y + bf1) + sigm(zw.y + bw1) * tanh_f(zi.y + bi1);
                float h0v = tanh_f(c0n) * sigm(zm.x + bm0);
                float h1v = tanh_f(c1n) * sigm(zm.y + bm1);
                creg0 = c0n; creg1 = c1n;
                const int wbuf = layer ? (t & 1) : (t % 3);
                unsigned short* tb = hown + (size_t)(wbuf * 2 + btile) * 32768;
                unsigned int packed = (unsigned int)f2bf(h0v) | ((unsigned int)f2bf(h1v) << 16);
                st32c((unsigned int*)(tb + hoff), packed);
                if (layer && t == T - 1) {
                    int idx = (brow + bl) * 1024 + colg;
                    out[idx] = h0v; out[idx + 1] = h1v;
                }
            }
        }

        // ---- publish phase completion ----
        if (p < P - 1) {
            __syncthreads();  // drains vmcnt: h-stores LLC-visible; WAR fence for a/z
            if (tid == 0) st32c(&flags[bid], (unsigned int)(p + 1));
        }
    }
}

// ---------------------------------------------------------------------------
extern "C" void kernel_launch(void* const* d_in, const int* in_sizes, int n_in,
                              void* d_out, int out_size, void* d_ws, size_t ws_size,
                              hipStream_t stream) {
    const float* seq = (const float*)d_in[0];
    const float* Wx0 = (const float*)d_in[1];
    const float* Wh0 = (const float*)d_in[2];
    const float* b0 = (const float*)d_in[3];
    const float* Wx1 = (const float*)d_in[4];
    const float* Wh1 = (const float*)d_in[5];
    const float* b1 = (const float*)d_in[6];
    float* out = (float*)d_out;
    char* ws = (char*)d_ws;
    const int T = 512;

    const size_t WBYTES = (size_t)4096 * 2048 * 2;         // 16.78 MB per layer
    const size_t SEQB_BYTES = (size_t)512 * 2 * 32768 * 2; // 67.1 MB (tile-major)
    const size_t H0_BYTES = 3 * 2 * 65536;                  // 3 bufs x 2 btiles
    const size_t H1_BYTES = 2 * 2 * 65536;
    const size_t STATE_BYTES = H0_BYTES + H1_BYTES + 1024;  // + flags

    size_t offSeqb = 2 * WBYTES;
    bool big = ws_size >= 2 * WBYTES + SEQB_BYTES + STATE_BYTES;
    size_t offState = big ? (offSeqb + SEQB_BYTES) : offSeqb;

    unsigned short* W0p = (unsigned short*)(ws);
    unsigned short* W1p = (unsigned short*)(ws + WBYTES);
    unsigned short* seqbp = (unsigned short*)(ws + offSeqb);
    unsigned short* h0p = (unsigned short*)(ws + offState);
    unsigned short* h1p = (unsigned short*)(ws + offState + H0_BYTES);
    unsigned int* flagsp = (unsigned int*)(ws + offState + H0_BYTES + H1_BYTES);

    hipLaunchKernelGGL(cvt_weights, dim3(8192), dim3(256), 0, stream,
                       Wx0, Wh0, Wx1, Wh1, W0p, W1p);
    if (big)
        hipLaunchKernelGGL(cvt_seq, dim3(T * 64), dim3(128), 0, stream, seq, seqbp, T);
    hipMemsetAsync(ws + offState, 0, STATE_BYTES, stream);

    int Tv = T;
    void* args[] = {&seq, &seqbp, &W0p, &W1p, &b0, &b1, &h0p, &h1p, &flagsp, &out, &Tv};
    if (big) {
        hipError_t e = hipLaunchCooperativeKernel((void*)lstm_persistent<true>,
                                                  dim3(256), dim3(256), args, 0, stream);
        if (e != hipSuccess) {
            // co-residency guaranteed by capacity (1 block/CU, 256 blocks);
            // the custom flag barrier needs no cooperative-launch semantics.
            hipLaunchKernelGGL((lstm_persistent<true>), dim3(256), dim3(256), 0, stream,
                               seq, seqbp, W0p, W1p, b0, b1, h0p, h1p, flagsp, out, Tv);
        }
    } else {
        hipError_t e = hipLaunchCooperativeKernel((void*)lstm_persistent<false>,
                                                  dim3(256), dim3(256), args, 0, stream);
        if (e != hipSuccess) {
            hipLaunchKernelGGL((lstm_persistent<false>), dim3(256), dim3(256), 0, stream,
                               seq, seqbp, W0p, W1p, b0, b1, h0p, h1p, flagsp, out, Tv);
        }
    }
}